// Round 5
// baseline (302.211 us; speedup 1.0000x reference)
//
#include <hip/hip_runtime.h>
#include <hip/hip_bf16.h>
#include <math.h>

// Problem constants: B=2, S=2048, E=1024, NH=4, DH=256
#define Bb  2
#define Ss  2048
#define Ee  1024
#define NHh 4
#define DHh 256
#define BH  (Bb*NHh)      // 8
#define TI  32            // i-rows per block
#define TJ  32            // j-cols per iteration

typedef short        s8v   __attribute__((ext_vector_type(8)));   // 8 bf16 (A/B frag)
typedef float        f4v   __attribute__((ext_vector_type(4)));   // 16x16 acc
typedef float        f16v  __attribute__((ext_vector_type(16)));  // 32x32 acc
typedef unsigned int u4v   __attribute__((ext_vector_type(4)));   // 16B LDS write
typedef unsigned int u2v   __attribute__((ext_vector_type(2)));   // 8B LDS write

// fp32 pair -> packed bf16x2 via HW v_cvt_pk_bf16_f32 (a = low 16)
__device__ inline unsigned pkbf2(float a, float b) {
    __hip_bfloat162 h2 = __float22bfloat162_rn(float2{a, b});
    unsigned u;
    __builtin_memcpy(&u, &h2, 4);
    return u;
}

// ---------------------------------------------------------------------------
// Kernel 1: gate pre-activations
// ---------------------------------------------------------------------------
__global__ __launch_bounds__(256) void gates_kernel(
    const float* __restrict__ q, const float* __restrict__ k, const float* __restrict__ v,
    const float* __restrict__ igw, const float* __restrict__ igb,
    const float* __restrict__ fgw, const float* __restrict__ fgb,
    float* __restrict__ ig_out, float* __restrict__ fg_out)
{
    int bs = blockIdx.x;
    int b = bs / Ss, s = bs % Ss;
    int tid = threadIdx.x;
    int c4 = tid * 4;
    float4 aq = *(const float4*)(q + (size_t)bs * Ee + c4);
    float4 ak = *(const float4*)(k + (size_t)bs * Ee + c4);
    float4 av = *(const float4*)(v + (size_t)bs * Ee + c4);

    float acc[8];
#pragma unroll
    for (int h = 0; h < NHh; h++) {
        const float* wi = igw + (size_t)h * 3 * Ee;
        const float* wf = fgw + (size_t)h * 3 * Ee;
        float4 wq, wk, wv;
        wq = *(const float4*)(wi + c4);
        wk = *(const float4*)(wi + Ee + c4);
        wv = *(const float4*)(wi + 2*Ee + c4);
        acc[2*h] = aq.x*wq.x + aq.y*wq.y + aq.z*wq.z + aq.w*wq.w
                 + ak.x*wk.x + ak.y*wk.y + ak.z*wk.z + ak.w*wk.w
                 + av.x*wv.x + av.y*wv.y + av.z*wv.z + av.w*wv.w;
        wq = *(const float4*)(wf + c4);
        wk = *(const float4*)(wf + Ee + c4);
        wv = *(const float4*)(wf + 2*Ee + c4);
        acc[2*h+1] = aq.x*wq.x + aq.y*wq.y + aq.z*wq.z + aq.w*wq.w
                   + ak.x*wk.x + ak.y*wk.y + ak.z*wk.z + ak.w*wk.w
                   + av.x*wv.x + av.y*wv.y + av.z*wv.z + av.w*wv.w;
    }
#pragma unroll
    for (int g = 0; g < 8; g++) {
        float x = acc[g];
        for (int off = 32; off > 0; off >>= 1) x += __shfl_down(x, off, 64);
        acc[g] = x;
    }
    __shared__ float part[4][8];
    int wid = tid >> 6, lane = tid & 63;
    if (lane == 0) {
#pragma unroll
        for (int g = 0; g < 8; g++) part[wid][g] = acc[g];
    }
    __syncthreads();
    if (tid < 8) {
        float t = part[0][tid] + part[1][tid] + part[2][tid] + part[3][tid];
        int h = tid >> 1;
        size_t o = ((size_t)(b * NHh + h)) * Ss + s;
        if (tid & 1) fg_out[o] = t + fgb[h];
        else         ig_out[o] = t + igb[h];
    }
}

// ---------------------------------------------------------------------------
// Kernel 2: per-(b,h) scans (unchanged)
// ---------------------------------------------------------------------------
#define CHUNK 8
__global__ __launch_bounds__(256) void scan_kernel(
    const float* __restrict__ ig, const float* __restrict__ fg,
    float* __restrict__ a_out, float* __restrict__ M_out, float* __restrict__ nf_out)
{
    int bh = blockIdx.x;
    int tid = threadIdx.x;
    const float* igp = ig + (size_t)bh * Ss;
    const float* fgp = fg + (size_t)bh * Ss;
    int s0 = tid * CHUNK;

    float ls[CHUNK], cs[CHUNK];
    float tot = 0.f;
#pragma unroll
    for (int c = 0; c < CHUNK; c++) {
        float x = fgp[s0 + c];
        float l = fminf(x, 0.f) - log1pf(expf(-fabsf(x)));
        ls[c] = l; tot += l; cs[c] = tot;
    }
    __shared__ float sc[256];
    sc[tid] = tot; __syncthreads();
    for (int off = 1; off < 256; off <<= 1) {
        float add = (tid >= off) ? sc[tid - off] : 0.f;
        __syncthreads();
        sc[tid] += add;
        __syncthreads();
    }
    float excl = sc[tid] - tot;

    float av[CHUNK], pmax[CHUNK];
    float tmax = -INFINITY;
#pragma unroll
    for (int c = 0; c < CHUNK; c++) {
        float csf  = excl + cs[c];
        float csm1 = csf - ls[c];
        float a = igp[s0 + c] - csm1;
        av[c] = a;
        tmax = fmaxf(tmax, a);
        pmax[c] = tmax;
        cs[c] = csf;
    }
    __shared__ float sm[256];
    sm[tid] = tmax; __syncthreads();
    for (int off = 1; off < 256; off <<= 1) {
        float other = (tid >= off) ? sm[tid - off] : -INFINITY;
        __syncthreads();
        sm[tid] = fmaxf(sm[tid], other);
        __syncthreads();
    }
    float emax = (tid > 0) ? sm[tid - 1] : -INFINITY;
#pragma unroll
    for (int c = 0; c < CHUNK; c++) {
        float M = fmaxf(emax, pmax[c]);
        size_t o = (size_t)bh * Ss + s0 + c;
        a_out[o]  = av[c];
        M_out[o]  = M;
        nf_out[o] = expf(-cs[c] - M);
    }
}

// ---------------------------------------------------------------------------
// Kernel 3: MFMA flash pass with FRAGMENT-ORDERED LDS tiles.
// All MFMA reads are base + lane*16B (conflict-free); staging writes are
// assigned by inverting the fragment map so thread t writes chunk t (linear).
// ---------------------------------------------------------------------------
template<bool SPLIT>
__global__ __launch_bounds__(256, 4) void mlstm_main(
    const float* __restrict__ qp, const float* __restrict__ kp, const float* __restrict__ vp,
    const float* __restrict__ a_ws, const float* __restrict__ M_ws, const float* __restrict__ nf_ws,
    const float* __restrict__ out_w, float* __restrict__ outF,
    float* __restrict__ Hpart, float* __restrict__ rsbuf)
{
    int bidx = blockIdx.x;
    int seg = 0, bh, T;
    if (SPLIT) {
        seg = bidx & 1;
        bh  = (bidx >> 1) & 7;
        T   = 63 - (bidx >> 4);          // heaviest-first (LPT scheduling)
    } else {
        int m4 = (bidx >> 1) & 15;
        int f  = ((bidx >> 8) & 1) ? (31 - 2 * m4) : (2 * m4);
        T  = (bidx & 1) ? (63 - f) : f;
        bh = (bidx >> 5) & 7;
    }
    int b = bh >> 2, h = bh & 3;
    int I0 = T * TI;
    int tid = threadIdx.x;

    int len = T + 1;
    int jt_beg = 0, jt_end = len;
    if (SPLIT) {
        int n0s = (len + 1) >> 1;
        jt_beg = seg ? n0s : 0;
        jt_end = seg ? len : n0s;
    }
    const size_t hoff = (size_t)h * DHh;
    float* Hdst = (SPLIT && seg) ? Hpart : outF;

    if (SPLIT && jt_beg >= jt_end) {      // empty segment: zero partials
        float4 z = {0.f, 0.f, 0.f, 0.f};
        for (int t = tid; t < TI * 64; t += 256) {
            int r = t >> 6, c = t & 63;
            *(float4*)(Hdst + ((size_t)(b * Ss + I0 + r)) * Ee + hoff + 4 * c) = z;
        }
        if (tid < TI) rsbuf[(size_t)seg * BH * Ss + (size_t)bh * Ss + I0 + tid] = 0.f;
        return;
    }

    // Fragment-ordered tiles: chunk D holds 8 bf16 at offset D*16B.
    //  KF: D = (jh*8+ks)*64 + lane        (A-frag of QK: S^T = K·Q^T), 16 KB
    //  VF: D = (2*n32+ks2g)*64 + lane     (B-frag of PV),              16 KB
    //  PF: D = ks2g*64 + lane             (A-frag of PV),               2 KB
    __shared__ union SU {
        struct {
            unsigned short KF[16 * 64 * 8];
            unsigned short VF[16 * 64 * 8];
            unsigned short PF[2 * 64 * 8];
        } s;
        float Hs[32][260];
    } su;
    __shared__ float a_s[TJ];
    __shared__ float rs_s[2][TI];
    __shared__ float inv_s[TI], mean_s[TI], rstd_s[TI];

    const int w    = tid >> 6;
    const int lane = tid & 63;
    const int jh = w & 1, ih = w >> 1;       // QK wave roles
    const int lm = lane & 15, q4 = lane >> 4;
    const int m5 = lane & 31, hl = lane >> 5;

    // ---- Q fragments cached in registers (B-operand of S^T = K·Q^T) ----
    s8v qf[8];
    {
        const float* qrow = qp + ((size_t)(b * Ss + I0 + ih * 16 + lm)) * Ee + hoff;
#pragma unroll
        for (int ks = 0; ks < 8; ks++) {
            const float4* p = (const float4*)(qrow + ks * 32 + q4 * 8);
            float4 x0 = p[0], x1 = p[1];
            union { s8v v; unsigned u[4]; } r;
            r.u[0] = pkbf2(x0.x, x0.y);
            r.u[1] = pkbf2(x0.z, x0.w);
            r.u[2] = pkbf2(x1.x, x1.y);
            r.u[3] = pkbf2(x1.z, x1.w);
            qf[ks] = r.v;
        }
    }
    const float Mi = M_ws[(size_t)bh * Ss + I0 + ih * 16 + lm];

    f16v acc0, acc1;
#pragma unroll
    for (int i = 0; i < 16; i++) { acc0[i] = 0.f; acc1[i] = 0.f; }
    float rs_acc = 0.f;

    const float inv_sqrt_dh = 0.0625f;

    // staging-role constants
    const int k_lm = tid & 15, k_slot = (tid >> 4) & 3;          // K staging
    const int v_d31 = tid & 31;                                   // V staging
    const int v_j0  = ((tid >> 6) & 1) * 16 + ((tid >> 5) & 1) * 8;

    for (int jt = jt_beg; jt < jt_end; jt++) {
        const int J0 = jt * TJ;
        __syncthreads();   // prior iteration's MFMA reads done before overwrite

        // ---- stage K tile into fragment order: thread t writes chunk p*256+t ----
#pragma unroll
        for (int p = 0; p < 4; p++) {
            int D = p * 256 + tid;
            int qq = D >> 6;                          // jh*8 + ks
            int jrow = (qq >> 3) * 16 + k_lm;
            int c0 = (qq & 7) * 32 + k_slot * 8;
            const float* src = kp + ((size_t)(b * Ss + J0 + jrow)) * Ee + hoff + c0;
            float4 x0 = ((const float4*)src)[0];
            float4 x1 = ((const float4*)src)[1];
            u4v wv;
            wv.x = pkbf2(x0.x, x0.y); wv.y = pkbf2(x0.z, x0.w);
            wv.z = pkbf2(x1.x, x1.y); wv.w = pkbf2(x1.z, x1.w);
            *(u4v*)&su.s.KF[D * 8] = wv;
        }
        // ---- stage V^T tile into fragment order (transpose: 8 j's per chunk) ----
#pragma unroll
        for (int p = 0; p < 4; p++) {
            int D = p * 256 + tid;
            int d = (D >> 7) * 32 + v_d31;
            const float* vb = vp + ((size_t)(b * Ss + J0 + v_j0)) * Ee + hoff + d;
            float e0 = vb[0];
            float e1 = vb[Ee];
            float e2 = vb[2 * Ee];
            float e3 = vb[3 * Ee];
            float e4 = vb[4 * Ee];
            float e5 = vb[5 * Ee];
            float e6 = vb[6 * Ee];
            float e7 = vb[7 * Ee];
            u4v wv;
            wv.x = pkbf2(e0, e1); wv.y = pkbf2(e2, e3);
            wv.z = pkbf2(e4, e5); wv.w = pkbf2(e6, e7);
            *(u4v*)&su.s.VF[D * 8] = wv;
        }
        if (tid < TJ) a_s[tid] = a_ws[(size_t)bh * Ss + J0 + tid];
        __syncthreads();

        // ---- QK: S^T tile [16j x 16i] per wave via mfma 16x16x32 ----
        f4v c = {0.f, 0.f, 0.f, 0.f};
#pragma unroll
        for (int ks = 0; ks < 8; ks++) {
            s8v af = *(const s8v*)&su.s.KF[((jh * 8 + ks) * 64 + lane) * 8];
            c = __builtin_amdgcn_mfma_f32_16x16x32_bf16(af, qf[ks], c, 0, 0, 0);
        }
        // decay + mask + pack P into PF fragment order
        {
            const int jb = jh * 16 + q4 * 4;
            const int ig = I0 + ih * 16 + lm;
            float p[4];
            float rsum = 0.f;
#pragma unroll
            for (int r = 0; r < 4; r++) {
                int jg = J0 + jb + r;
                float pv = 0.f;
                if (jg <= ig) pv = c[r] * inv_sqrt_dh * __expf(a_s[jb + r] - Mi);
                p[r] = pv; rsum += pv;
            }
            u2v pw;
            pw.x = pkbf2(p[0], p[1]);
            pw.y = pkbf2(p[2], p[3]);
            // chunk D_P = jh*64 + (q4>>1)*32 + i ; half-chunk offset (q4&1)*4
            int D_P = jh * 64 + (q4 >> 1) * 32 + ih * 16 + lm;
            *(u2v*)&su.s.PF[D_P * 8 + (q4 & 1) * 4] = pw;
            rsum += __shfl_xor(rsum, 16);
            rsum += __shfl_xor(rsum, 32);
            rs_acc += rsum;
        }
        __syncthreads();

        // ---- PV: H[32 x 256] += P[32 x 32] · V[32 x 256] via mfma 32x32x16 ----
#pragma unroll
        for (int g = 0; g < 2; g++) {
            s8v pa  = *(const s8v*)&su.s.PF[(g * 64 + lane) * 8];
            s8v vb0 = *(const s8v*)&su.s.VF[((4 * w + g) * 64 + lane) * 8];
            s8v vb1 = *(const s8v*)&su.s.VF[((4 * w + 2 + g) * 64 + lane) * 8];
            acc0 = __builtin_amdgcn_mfma_f32_32x32x16_bf16(pa, vb0, acc0, 0, 0, 0);
            acc1 = __builtin_amdgcn_mfma_f32_32x32x16_bf16(pa, vb1, acc1, 0, 0, 0);
        }
    }

    // ---- epilogue ----
    if (lane < 16) rs_s[jh][ih * 16 + lm] = rs_acc;
    __syncthreads();

    if (SPLIT) {
        if (tid < TI)
            rsbuf[(size_t)seg * BH * Ss + (size_t)bh * Ss + I0 + tid] = rs_s[0][tid] + rs_s[1][tid];
        // dump raw fp32 partial H (32x32 C-layout: col=m5, row=(r&3)+8*(r>>2)+4*hl)
#pragma unroll
        for (int nt = 0; nt < 2; nt++) {
#pragma unroll
            for (int r = 0; r < 16; r++) {
                int m = (r & 3) + 8 * (r >> 2) + 4 * hl;
                su.Hs[m][w * 64 + nt * 32 + m5] = nt ? acc1[r] : acc0[r];
            }
        }
        __syncthreads();
        {
            int i = tid >> 3, sg = tid & 7;
            float* orow = Hdst + ((size_t)(b * Ss + I0 + i)) * Ee + hoff;
#pragma unroll
            for (int c4 = 0; c4 < 8; c4++) {
                int d = sg * 32 + c4 * 4;
                *(float4*)(orow + d) = *(const float4*)&su.Hs[i][d];
            }
        }
        return;
    }

    // non-split: full normalize + group-norm epilogue
    if (tid < TI) {
        float r = rs_s[0][tid] + rs_s[1][tid];
        float nfv = nf_ws[(size_t)bh * Ss + I0 + tid];
        float n = fmaxf(fabsf(r), nfv) + 1e-8f;
        inv_s[tid] = 1.f / n;
    }
    __syncthreads();
#pragma unroll
    for (int nt = 0; nt < 2; nt++) {
#pragma unroll
        for (int r = 0; r < 16; r++) {
            int m = (r & 3) + 8 * (r >> 2) + 4 * hl;
            float x = (nt ? acc1[r] : acc0[r]) * inv_s[m];
            su.Hs[m][w * 64 + nt * 32 + m5] = x;
        }
    }
    __syncthreads();
    {
        int i = tid >> 3, sg = tid & 7;
        float sx = 0.f, sq = 0.f;
#pragma unroll
        for (int c4 = 0; c4 < 8; c4++) {
            float4 hv = *(const float4*)&su.Hs[i][sg * 32 + c4 * 4];
            sx += hv.x + hv.y + hv.z + hv.w;
            sq += hv.x*hv.x + hv.y*hv.y + hv.z*hv.z + hv.w*hv.w;
        }
        sx += __shfl_xor(sx, 1); sq += __shfl_xor(sq, 1);
        sx += __shfl_xor(sx, 2); sq += __shfl_xor(sq, 2);
        sx += __shfl_xor(sx, 4); sq += __shfl_xor(sq, 4);
        if (sg == 0) {
            float mean = sx * (1.f / DHh);
            float var  = sq * (1.f / DHh) - mean * mean;
            mean_s[i] = mean;
            rstd_s[i] = rsqrtf(var + 1e-5f);
        }
    }
    __syncthreads();
    {
        int i = tid >> 3, sg = tid & 7;
        float mean = mean_s[i], rstd = rstd_s[i];
        float* orow = outF + ((size_t)(b * Ss + I0 + i)) * Ee + hoff;
        const float* ow = out_w + hoff;
#pragma unroll
        for (int c4 = 0; c4 < 8; c4++) {
            int d = sg * 32 + c4 * 4;
            float4 hv = *(const float4*)&su.Hs[i][d];
            float4 w4 = *(const float4*)&ow[d];
            float4 o;
            o.x = (hv.x - mean) * rstd * (1.f + w4.x);
            o.y = (hv.y - mean) * rstd * (1.f + w4.y);
            o.z = (hv.z - mean) * rstd * (1.f + w4.z);
            o.w = (hv.w - mean) * rstd * (1.f + w4.w);
            *(float4*)(orow + d) = o;
        }
    }
}

// ---------------------------------------------------------------------------
// Kernel 4 (SPLIT path): combine partials, normalize, group-norm. 1 wave/row.
// ---------------------------------------------------------------------------
__global__ __launch_bounds__(256) void combine_kernel(
    const float* __restrict__ Hb, const float* __restrict__ rsbuf,
    const float* __restrict__ nf_ws, const float* __restrict__ out_w,
    float* __restrict__ outF)
{
    int rid = blockIdx.x * 4 + (threadIdx.x >> 6);   // row over BH*S
    int lane = threadIdx.x & 63;
    int bh = rid >> 11, s = rid & 2047;
    int b = bh >> 2, h = bh & 3;
    size_t base = ((size_t)(b * Ss + s)) * Ee + (size_t)h * DHh + lane * 4;
    float4 ha = *(const float4*)(outF + base);
    float4 hb = *(const float4*)(Hb + base);
    float rs = rsbuf[(size_t)bh * Ss + s] + rsbuf[(size_t)BH * Ss + (size_t)bh * Ss + s];
    float nfv = nf_ws[(size_t)bh * Ss + s];
    float invn = 1.f / (fmaxf(fabsf(rs), nfv) + 1e-8f);
    float4 x;
    x.x = (ha.x + hb.x) * invn;
    x.y = (ha.y + hb.y) * invn;
    x.z = (ha.z + hb.z) * invn;
    x.w = (ha.w + hb.w) * invn;
    float sx = x.x + x.y + x.z + x.w;
    float sq = x.x*x.x + x.y*x.y + x.z*x.z + x.w*x.w;
#pragma unroll
    for (int off = 1; off < 64; off <<= 1) {
        sx += __shfl_xor(sx, off);
        sq += __shfl_xor(sq, off);
    }
    float mean = sx * (1.f / DHh);
    float var  = sq * (1.f / DHh) - mean * mean;
    float rstd = rsqrtf(var + 1e-5f);
    float4 w4 = *(const float4*)(out_w + (size_t)h * DHh + lane * 4);
    float4 o;
    o.x = (x.x - mean) * rstd * (1.f + w4.x);
    o.y = (x.y - mean) * rstd * (1.f + w4.y);
    o.z = (x.z - mean) * rstd * (1.f + w4.z);
    o.w = (x.w - mean) * rstd * (1.f + w4.w);
    *(float4*)(outF + base) = o;
}

// ---------------------------------------------------------------------------
extern "C" void kernel_launch(void* const* d_in, const int* in_sizes, int n_in,
                              void* d_out, int out_size, void* d_ws, size_t ws_size,
                              hipStream_t stream) {
    const float* q   = (const float*)d_in[0];
    const float* k   = (const float*)d_in[1];
    const float* v   = (const float*)d_in[2];
    const float* igw = (const float*)d_in[3];
    const float* igb = (const float*)d_in[4];
    const float* fgw = (const float*)d_in[5];
    const float* fgb = (const float*)d_in[6];
    const float* ow  = (const float*)d_in[7];
    float* out = (float*)d_out;

    float* ws = (float*)d_ws;
    float* ig = ws;                     // BH*S floats each
    float* fg = ws + 16384;
    float* aa = ws + 32768;
    float* MM = ws + 49152;
    float* nf = ws + 65536;
    float* rsb   = ws + 81920;          // 2 * BH * S floats
    float* Hpart = ws + 114688;         // B*S*E floats = 16 MB

    const size_t need = (size_t)(114688 + Bb * Ss * Ee) * 4;
    const bool split = ws_size >= need;

    gates_kernel<<<Bb * Ss, 256, 0, stream>>>(q, k, v, igw, igb, fgw, fgb, ig, fg);
    scan_kernel<<<BH, 256, 0, stream>>>(ig, fg, aa, MM, nf);
    if (split) {
        mlstm_main<true><<<1024, 256, 0, stream>>>(q, k, v, aa, MM, nf, ow, out, Hpart, rsb);
        combine_kernel<<<BH * Ss / 4, 256, 0, stream>>>(Hpart, rsb, nf, ow, out);
    } else {
        mlstm_main<false><<<512, 256, 0, stream>>>(q, k, v, aa, MM, nf, ow, out, Hpart, rsb);
    }
}

// Round 6
// 249.483 us; speedup vs baseline: 1.2113x; 1.2113x over previous
//
#include <hip/hip_runtime.h>
#include <hip/hip_bf16.h>
#include <math.h>

// Problem constants: B=2, S=2048, E=1024, NH=4, DH=256
#define Bb  2
#define Ss  2048
#define Ee  1024
#define NHh 4
#define DHh 256
#define BH  (Bb*NHh)      // 8
#define TI  64            // i-rows per block
#define TJ  32            // j-cols per iteration
#define NT2 (Ss/TI)       // 32 i-tiles per bh

typedef short        s8v   __attribute__((ext_vector_type(8)));   // 8 bf16 (A/B frag)
typedef float        f4v   __attribute__((ext_vector_type(4)));   // 16x16 acc
typedef float        f16v  __attribute__((ext_vector_type(16)));  // 32x32 acc
typedef unsigned int u4v   __attribute__((ext_vector_type(4)));   // 16B LDS write
typedef unsigned int u2v   __attribute__((ext_vector_type(2)));   // 8B LDS write

// fp32 pair -> packed bf16x2 via HW v_cvt_pk_bf16_f32 (a = low 16)
__device__ inline unsigned pkbf2(float a, float b) {
    __hip_bfloat162 h2 = __float22bfloat162_rn(float2{a, b});
    unsigned u;
    __builtin_memcpy(&u, &h2, 4);
    return u;
}

// ---------------------------------------------------------------------------
// Kernel 1: gates. Weights (4 combos x 3072) staged ONCE in LDS per block;
// each block handles 16 (b,s) rows x 2 heads. Kills the 400MB weight re-read.
// grid = 512: bidx = sc*2 + hp  (sc: 16-row chunk, hp: head pair)
// ---------------------------------------------------------------------------
__global__ __launch_bounds__(256) void gates_kernel(
    const float* __restrict__ q, const float* __restrict__ k, const float* __restrict__ v,
    const float* __restrict__ igw, const float* __restrict__ igb,
    const float* __restrict__ fgw, const float* __restrict__ fgb,
    float* __restrict__ ig_out, float* __restrict__ fg_out)
{
    int bidx = blockIdx.x;
    int sc = bidx >> 1, hp = bidx & 1;
    int tid = threadIdx.x;
    __shared__ float wl[4][3072];          // 48 KB
    __shared__ float pw[4][4];

#pragma unroll
    for (int c = 0; c < 4; c++) {
        int h = hp * 2 + (c >> 1);
        const float* src = ((c & 1) ? fgw : igw) + (size_t)h * 3 * Ee;
        for (int idx = tid * 4; idx < 3 * Ee; idx += 1024)
            *(float4*)&wl[c][idx] = *(const float4*)(src + idx);
    }
    __syncthreads();

    int c4 = tid * 4;
    int w = tid >> 6, lane = tid & 63;

    for (int ss = 0; ss < 16; ss++) {
        int bs = sc * 16 + ss;
        float4 q4v = *(const float4*)(q + (size_t)bs * Ee + c4);
        float4 k4v = *(const float4*)(k + (size_t)bs * Ee + c4);
        float4 v4v = *(const float4*)(v + (size_t)bs * Ee + c4);
        float red[4];
#pragma unroll
        for (int c = 0; c < 4; c++) {
            const float* wc = wl[c];
            float4 wq = *(const float4*)&wc[c4];
            float4 wk = *(const float4*)&wc[Ee + c4];
            float4 wv = *(const float4*)&wc[2 * Ee + c4];
            float x = q4v.x*wq.x + q4v.y*wq.y + q4v.z*wq.z + q4v.w*wq.w
                    + k4v.x*wk.x + k4v.y*wk.y + k4v.z*wk.z + k4v.w*wk.w
                    + v4v.x*wv.x + v4v.y*wv.y + v4v.z*wv.z + v4v.w*wv.w;
            for (int off = 32; off > 0; off >>= 1) x += __shfl_down(x, off, 64);
            red[c] = x;
        }
        __syncthreads();                    // pw reuse from previous ss
        if (lane == 0) {
#pragma unroll
            for (int c = 0; c < 4; c++) pw[w][c] = red[c];
        }
        __syncthreads();
        if (tid < 4) {
            float t = pw[0][tid] + pw[1][tid] + pw[2][tid] + pw[3][tid];
            int h = hp * 2 + (tid >> 1);
            int b = bs >> 11, s = bs & 2047;
            size_t o = ((size_t)(b * NHh + h)) * Ss + s;
            if (tid & 1) fg_out[o] = t + fgb[h];
            else         ig_out[o] = t + igb[h];
        }
    }
}

// ---------------------------------------------------------------------------
// Kernel 2: per-(b,h) scans (unchanged)
// ---------------------------------------------------------------------------
#define CHUNK 8
__global__ __launch_bounds__(256) void scan_kernel(
    const float* __restrict__ ig, const float* __restrict__ fg,
    float* __restrict__ a_out, float* __restrict__ M_out, float* __restrict__ nf_out)
{
    int bh = blockIdx.x;
    int tid = threadIdx.x;
    const float* igp = ig + (size_t)bh * Ss;
    const float* fgp = fg + (size_t)bh * Ss;
    int s0 = tid * CHUNK;

    float ls[CHUNK], cs[CHUNK];
    float tot = 0.f;
#pragma unroll
    for (int c = 0; c < CHUNK; c++) {
        float x = fgp[s0 + c];
        float l = fminf(x, 0.f) - log1pf(expf(-fabsf(x)));
        ls[c] = l; tot += l; cs[c] = tot;
    }
    __shared__ float sc[256];
    sc[tid] = tot; __syncthreads();
    for (int off = 1; off < 256; off <<= 1) {
        float add = (tid >= off) ? sc[tid - off] : 0.f;
        __syncthreads();
        sc[tid] += add;
        __syncthreads();
    }
    float excl = sc[tid] - tot;

    float av[CHUNK], pmax[CHUNK];
    float tmax = -INFINITY;
#pragma unroll
    for (int c = 0; c < CHUNK; c++) {
        float csf  = excl + cs[c];
        float csm1 = csf - ls[c];
        float a = igp[s0 + c] - csm1;
        av[c] = a;
        tmax = fmaxf(tmax, a);
        pmax[c] = tmax;
        cs[c] = csf;
    }
    __shared__ float sm[256];
    sm[tid] = tmax; __syncthreads();
    for (int off = 1; off < 256; off <<= 1) {
        float other = (tid >= off) ? sm[tid - off] : -INFINITY;
        __syncthreads();
        sm[tid] = fmaxf(sm[tid], other);
        __syncthreads();
    }
    float emax = (tid > 0) ? sm[tid - 1] : -INFINITY;
#pragma unroll
    for (int c = 0; c < CHUNK; c++) {
        float M = fmaxf(emax, pmax[c]);
        size_t o = (size_t)bh * Ss + s0 + c;
        a_out[o]  = av[c];
        M_out[o]  = M;
        nf_out[o] = expf(-cs[c] - M);
    }
}

// ---------------------------------------------------------------------------
// Kernel 3: MFMA flash pass, TI=64, XOR-swizzled LDS (conflict-free reads AND
// writes, coalesced global staging). Always writes fp32 partial H + rowsums;
// combine kernel finishes. PARTS=2: j-range split at T+1 (exactly balanced).
// ---------------------------------------------------------------------------
template<int PARTS>
__global__ __launch_bounds__(256, 3) void mlstm_main(
    const float* __restrict__ qp, const float* __restrict__ kp, const float* __restrict__ vp,
    const float* __restrict__ a_ws, const float* __restrict__ M_ws,
    float* __restrict__ outF, float* __restrict__ Hpart, float* __restrict__ rsbuf)
{
    int bidx = blockIdx.x;
    int seg, bh, T;
    if (PARTS == 2) {
        seg = bidx & 1;
        bh  = (bidx >> 1) & 7;
        T   = (NT2 - 1) - (bidx >> 4);     // LPT: heaviest first
    } else {
        seg = 0;
        bh  = bidx & 7;
        T   = (NT2 - 1) - (bidx >> 3);
    }
    int b = bh >> 2, h = bh & 3;
    int I0 = T * TI;
    int tid = threadIdx.x;

    int jt_beg = (PARTS == 2 && seg) ? (T + 1) : 0;
    int jt_end = (PARTS == 2 && !seg) ? (T + 1) : (2 * T + 2);
    const size_t hoff = (size_t)h * DHh;
    float* Hdst = (PARTS == 2 && seg) ? Hpart : outF;

    // Swizzled chunk layouts (chunk = 16B = 8 bf16):
    //  KF (32 j-rows x 32 cc):  chunk(row,cc) at row*32 + (cc ^ (row&7))
    //  VF (256 d-rows x 4 jc):  chunk(d,jc)  at d*4 + (jc ^ ((d>>1)&3))
    //  PF (64 i-rows x 4 kb):   chunk(i,kb)  at i*4 + (kb ^ ((i>>1)&3))
    __shared__ unsigned short KF[1024 * 8];   // 16 KB
    __shared__ unsigned short VF[1024 * 8];   // 16 KB
    __shared__ unsigned short PF[256 * 8];    //  4 KB
    __shared__ float a_s[TJ];
    __shared__ float rs_s[TI];

    const int iq   = tid >> 6;       // wave = i-quarter
    const int lane = tid & 63;
    const int lm = lane & 15, q4 = lane >> 4;
    const int m5 = lane & 31, hl = lane >> 5;

    // ---- Q fragments in registers (B-operand of S^T = K·Q^T), 8 s8v ----
    s8v qf[8];
    {
        const float* qrow = qp + ((size_t)(b * Ss + I0 + iq * 16 + lm)) * Ee + hoff;
#pragma unroll
        for (int ks = 0; ks < 8; ks++) {
            const float4* p = (const float4*)(qrow + ks * 32 + q4 * 8);
            float4 x0 = p[0], x1 = p[1];
            union { s8v v; unsigned u[4]; } r;
            r.u[0] = pkbf2(x0.x, x0.y);
            r.u[1] = pkbf2(x0.z, x0.w);
            r.u[2] = pkbf2(x1.x, x1.y);
            r.u[3] = pkbf2(x1.z, x1.w);
            qf[ks] = r.v;
        }
    }
    const int  i_row = I0 + iq * 16 + lm;                 // this lane's i (QK role)
    const float Mi = M_ws[(size_t)bh * Ss + i_row];

    f16v acc[4];                                          // [im*2 + ns]
#pragma unroll
    for (int t = 0; t < 4; t++)
#pragma unroll
        for (int i = 0; i < 16; i++) acc[t][i] = 0.f;
    float rs_acc = 0.f;

    const float inv_sqrt_dh = 0.0625f;
    const int kR  = tid >> 3, kc0 = tid & 7;              // K staging role
    const int vdp = tid & 127, vjb = tid >> 7;            // V staging role

    for (int jt = jt_beg; jt < jt_end; jt++) {
        const int J0 = jt * TJ;
        __syncthreads();   // prior iteration's MFMA reads done before overwrite

        // ---- stage K tile (rows j): 8 lanes/row, 256B contiguous per row ----
        {
            const float* src = kp + ((size_t)(b * Ss + J0 + kR)) * Ee + hoff;
#pragma unroll
            for (int p = 0; p < 4; p++) {
                int cc = kc0 + 8 * p;
                float4 x0 = ((const float4*)(src + cc * 8))[0];
                float4 x1 = ((const float4*)(src + cc * 8))[1];
                u4v wv;
                wv.x = pkbf2(x0.x, x0.y); wv.y = pkbf2(x0.z, x0.w);
                wv.z = pkbf2(x1.x, x1.y); wv.w = pkbf2(x1.z, x1.w);
                *(u4v*)&KF[(kR * 32 + (cc ^ (kR & 7))) * 8] = wv;
            }
        }
        // ---- stage V^T tile: thread = d-pair x 8-j group, float2 loads ----
        {
            int d0 = vdp * 2;
#pragma unroll
            for (int p = 0; p < 2; p++) {
                int jc = vjb + 2 * p;
                const float* vbase = vp + ((size_t)(b * Ss + J0 + jc * 8)) * Ee + hoff + d0;
                float2 e0 = *(const float2*)(vbase);
                float2 e1 = *(const float2*)(vbase + Ee);
                float2 e2 = *(const float2*)(vbase + 2 * Ee);
                float2 e3 = *(const float2*)(vbase + 3 * Ee);
                float2 e4 = *(const float2*)(vbase + 4 * Ee);
                float2 e5 = *(const float2*)(vbase + 5 * Ee);
                float2 e6 = *(const float2*)(vbase + 6 * Ee);
                float2 e7 = *(const float2*)(vbase + 7 * Ee);
                int swz = jc ^ ((d0 >> 1) & 3);
                u4v w0, w1;
                w0.x = pkbf2(e0.x, e1.x); w0.y = pkbf2(e2.x, e3.x);
                w0.z = pkbf2(e4.x, e5.x); w0.w = pkbf2(e6.x, e7.x);
                w1.x = pkbf2(e0.y, e1.y); w1.y = pkbf2(e2.y, e3.y);
                w1.z = pkbf2(e4.y, e5.y); w1.w = pkbf2(e6.y, e7.y);
                *(u4v*)&VF[(d0 * 4 + swz) * 8] = w0;
                *(u4v*)&VF[((d0 + 1) * 4 + swz) * 8] = w1;
            }
        }
        if (tid < TJ) a_s[tid] = a_ws[(size_t)bh * Ss + J0 + tid];
        __syncthreads();

        // ---- QK: S^T [32j x 16i] per wave via mfma 16x16x32 (both j-halves) ----
        f4v c0 = {0.f, 0.f, 0.f, 0.f}, c1 = c0;
#pragma unroll
        for (int ks = 0; ks < 8; ks++) {
            int swzk = ((ks * 4 + q4) ^ (lm & 7)) * 8;
            s8v af0 = *(const s8v*)&KF[(lm * 32) * 8 + swzk];
            s8v af1 = *(const s8v*)&KF[((16 + lm) * 32) * 8 + swzk];
            c0 = __builtin_amdgcn_mfma_f32_16x16x32_bf16(af0, qf[ks], c0, 0, 0, 0);
            c1 = __builtin_amdgcn_mfma_f32_16x16x32_bf16(af1, qf[ks], c1, 0, 0, 0);
        }
        // decay + mask + pack P into PF (swizzled), accumulate signed rowsum
        {
            float rsum = 0.f;
#pragma unroll
            for (int t = 0; t < 2; t++) {
                const f4v cc = t ? c1 : c0;
                const int jb = t * 16 + q4 * 4;
                float p[4];
#pragma unroll
                for (int r = 0; r < 4; r++) {
                    int jg = J0 + jb + r;
                    float pv = 0.f;
                    if (jg <= i_row) pv = cc[r] * inv_sqrt_dh * __expf(a_s[jb + r] - Mi);
                    p[r] = pv; rsum += pv;
                }
                u2v pwv;
                pwv.x = pkbf2(p[0], p[1]);
                pwv.y = pkbf2(p[2], p[3]);
                int i = iq * 16 + lm;
                int kb = t * 2 + (q4 >> 1);
                *(u2v*)&PF[(i * 4 + (kb ^ ((i >> 1) & 3))) * 8 + (q4 & 1) * 4] = pwv;
            }
            rsum += __shfl_xor(rsum, 16);
            rsum += __shfl_xor(rsum, 32);
            rs_acc += rsum;
        }
        __syncthreads();

        // ---- PV: H[64 x 256] += P[64 x 32] · V[32 x 256] via mfma 32x32x16 ----
#pragma unroll
        for (int ks2 = 0; ks2 < 2; ks2++) {
            int swz2 = ((ks2 * 2 + hl) ^ ((m5 >> 1) & 3)) * 8;
            s8v pa0 = *(const s8v*)&PF[(m5 * 4) * 8 + swz2];
            s8v pa1 = *(const s8v*)&PF[((32 + m5) * 4) * 8 + swz2];
            s8v vb0 = *(const s8v*)&VF[((iq * 32 + m5) * 4) * 8 + swz2];
            s8v vb1 = *(const s8v*)&VF[(((iq + 4) * 32 + m5) * 4) * 8 + swz2];
            acc[0] = __builtin_amdgcn_mfma_f32_32x32x16_bf16(pa0, vb0, acc[0], 0, 0, 0);
            acc[1] = __builtin_amdgcn_mfma_f32_32x32x16_bf16(pa0, vb1, acc[1], 0, 0, 0);
            acc[2] = __builtin_amdgcn_mfma_f32_32x32x16_bf16(pa1, vb0, acc[2], 0, 0, 0);
            acc[3] = __builtin_amdgcn_mfma_f32_32x32x16_bf16(pa1, vb1, acc[3], 0, 0, 0);
        }
    }

    // ---- epilogue: rowsums + raw fp32 partial H straight from accs ----
    if (q4 == 0) rs_s[iq * 16 + lm] = rs_acc;
    __syncthreads();
    if (tid < TI)
        rsbuf[(size_t)seg * BH * Ss + (size_t)bh * Ss + I0 + tid] = rs_s[tid];

#pragma unroll
    for (int im = 0; im < 2; im++)
#pragma unroll
        for (int ns = 0; ns < 2; ns++) {
            const f16v av = acc[im * 2 + ns];
            const int col = (iq + 4 * ns) * 32 + m5;
#pragma unroll
            for (int r = 0; r < 16; r++) {
                int row = I0 + im * 32 + (r & 3) + 8 * (r >> 2) + 4 * hl;
                Hdst[((size_t)(b * Ss + row)) * Ee + hoff + col] = av[r];
            }
        }
}

// ---------------------------------------------------------------------------
// Kernel 4: combine partials, normalize, group-norm. 1 wave per row.
// ---------------------------------------------------------------------------
template<int PARTS>
__global__ __launch_bounds__(256) void combine_kernel(
    const float* __restrict__ Hb, const float* __restrict__ rsbuf,
    const float* __restrict__ nf_ws, const float* __restrict__ out_w,
    float* __restrict__ outF)
{
    int rid = blockIdx.x * 4 + (threadIdx.x >> 6);   // row over BH*S
    int lane = threadIdx.x & 63;
    int bh = rid >> 11, s = rid & 2047;
    int b = bh >> 2, h = bh & 3;
    size_t base = ((size_t)(b * Ss + s)) * Ee + (size_t)h * DHh + lane * 4;
    float4 ha = *(const float4*)(outF + base);
    float rs = rsbuf[(size_t)bh * Ss + s];
    if (PARTS == 2) {
        float4 hb = *(const float4*)(Hb + base);
        ha.x += hb.x; ha.y += hb.y; ha.z += hb.z; ha.w += hb.w;
        rs += rsbuf[(size_t)BH * Ss + (size_t)bh * Ss + s];
    }
    float nfv = nf_ws[(size_t)bh * Ss + s];
    float invn = 1.f / (fmaxf(fabsf(rs), nfv) + 1e-8f);
    float4 x;
    x.x = ha.x * invn; x.y = ha.y * invn; x.z = ha.z * invn; x.w = ha.w * invn;
    float sx = x.x + x.y + x.z + x.w;
    float sq = x.x*x.x + x.y*x.y + x.z*x.z + x.w*x.w;
#pragma unroll
    for (int off = 1; off < 64; off <<= 1) {
        sx += __shfl_xor(sx, off);
        sq += __shfl_xor(sq, off);
    }
    float mean = sx * (1.f / DHh);
    float var  = sq * (1.f / DHh) - mean * mean;
    float rstd = rsqrtf(var + 1e-5f);
    float4 w4 = *(const float4*)(out_w + (size_t)h * DHh + lane * 4);
    float4 o;
    o.x = (x.x - mean) * rstd * (1.f + w4.x);
    o.y = (x.y - mean) * rstd * (1.f + w4.y);
    o.z = (x.z - mean) * rstd * (1.f + w4.z);
    o.w = (x.w - mean) * rstd * (1.f + w4.w);
    *(float4*)(outF + base) = o;
}

// ---------------------------------------------------------------------------
extern "C" void kernel_launch(void* const* d_in, const int* in_sizes, int n_in,
                              void* d_out, int out_size, void* d_ws, size_t ws_size,
                              hipStream_t stream) {
    const float* q   = (const float*)d_in[0];
    const float* k   = (const float*)d_in[1];
    const float* v   = (const float*)d_in[2];
    const float* igw = (const float*)d_in[3];
    const float* igb = (const float*)d_in[4];
    const float* fgw = (const float*)d_in[5];
    const float* fgb = (const float*)d_in[6];
    const float* ow  = (const float*)d_in[7];
    float* out = (float*)d_out;

    float* ws = (float*)d_ws;
    float* ig = ws;                     // BH*S floats each
    float* fg = ws + 16384;
    float* aa = ws + 32768;
    float* MM = ws + 49152;
    float* nf = ws + 65536;
    float* rsb   = ws + 81920;          // 2 * BH * S floats
    float* Hpart = ws + 114688;         // B*S*E floats = 16 MB

    const size_t need = (size_t)(114688 + Bb * Ss * Ee) * 4;
    const bool split = ws_size >= need;

    gates_kernel<<<512, 256, 0, stream>>>(q, k, v, igw, igb, fgw, fgb, ig, fg);
    scan_kernel<<<BH, 256, 0, stream>>>(ig, fg, aa, MM, nf);
    if (split) {
        mlstm_main<2><<<BH * NT2 * 2, 256, 0, stream>>>(q, k, v, aa, MM, out, Hpart, rsb);
        combine_kernel<2><<<BH * Ss / 4, 256, 0, stream>>>(Hpart, rsb, nf, ow, out);
    } else {
        mlstm_main<1><<<BH * NT2, 256, 0, stream>>>(q, k, v, aa, MM, out, Hpart, rsb);
        combine_kernel<1><<<BH * Ss / 4, 256, 0, stream>>>(Hpart, rsb, nf, ow, out);
    }
}

// Round 7
// 246.738 us; speedup vs baseline: 1.2248x; 1.0111x over previous
//
#include <hip/hip_runtime.h>
#include <hip/hip_bf16.h>
#include <math.h>

// Problem constants: B=2, S=2048, E=1024, NH=4, DH=256
#define Bb  2
#define Ss  2048
#define Ee  1024
#define NHh 4
#define DHh 256
#define BH  (Bb*NHh)      // 8
#define TI  64            // i-rows per block
#define TJ  32            // j-cols per iteration
#define NT2 (Ss/TI)       // 32 i-tiles per bh
#define NJT (Ss/TJ)       // 64 j-tiles per bh

typedef short        s8v   __attribute__((ext_vector_type(8)));   // 8 bf16 (A/B frag)
typedef float        f4v   __attribute__((ext_vector_type(4)));   // 16x16 acc
typedef float        f16v  __attribute__((ext_vector_type(16)));  // 32x32 acc
typedef unsigned int u4v   __attribute__((ext_vector_type(4)));   // 16B LDS write
typedef unsigned int u2v   __attribute__((ext_vector_type(2)));   // 8B LDS write

// fp32 pair -> packed bf16x2 via HW v_cvt_pk_bf16_f32 (a = low 16)
__device__ inline unsigned pkbf2(float a, float b) {
    __hip_bfloat162 h2 = __float22bfloat162_rn(float2{a, b});
    unsigned u;
    __builtin_memcpy(&u, &h2, 4);
    return u;
}

// async 16B global->LDS DMA; lds arg must be wave-uniform (HW adds lane*16)
__device__ inline void async16(const void* g, void* l) {
    __builtin_amdgcn_global_load_lds(
        (const __attribute__((address_space(1))) void*)g,
        (__attribute__((address_space(3))) void*)l, 16, 0, 0);
}

// ---------------------------------------------------------------------------
// Kernel 1: gates. Weights staged once in LDS per block; 16 rows x 2 heads.
// ---------------------------------------------------------------------------
__global__ __launch_bounds__(256) void gates_kernel(
    const float* __restrict__ q, const float* __restrict__ k, const float* __restrict__ v,
    const float* __restrict__ igw, const float* __restrict__ igb,
    const float* __restrict__ fgw, const float* __restrict__ fgb,
    float* __restrict__ ig_out, float* __restrict__ fg_out)
{
    int bidx = blockIdx.x;
    int sc = bidx >> 1, hp = bidx & 1;
    int tid = threadIdx.x;
    __shared__ float wl[4][3072];          // 48 KB
    __shared__ float pw[4][4];

#pragma unroll
    for (int c = 0; c < 4; c++) {
        int h = hp * 2 + (c >> 1);
        const float* src = ((c & 1) ? fgw : igw) + (size_t)h * 3 * Ee;
        for (int idx = tid * 4; idx < 3 * Ee; idx += 1024)
            *(float4*)&wl[c][idx] = *(const float4*)(src + idx);
    }
    __syncthreads();

    int c4 = tid * 4;
    int w = tid >> 6, lane = tid & 63;

    for (int ss = 0; ss < 16; ss++) {
        int bs = sc * 16 + ss;
        float4 q4v = *(const float4*)(q + (size_t)bs * Ee + c4);
        float4 k4v = *(const float4*)(k + (size_t)bs * Ee + c4);
        float4 v4v = *(const float4*)(v + (size_t)bs * Ee + c4);
        float red[4];
#pragma unroll
        for (int c = 0; c < 4; c++) {
            const float* wc = wl[c];
            float4 wq = *(const float4*)&wc[c4];
            float4 wk = *(const float4*)&wc[Ee + c4];
            float4 wv = *(const float4*)&wc[2 * Ee + c4];
            float x = q4v.x*wq.x + q4v.y*wq.y + q4v.z*wq.z + q4v.w*wq.w
                    + k4v.x*wk.x + k4v.y*wk.y + k4v.z*wk.z + k4v.w*wk.w
                    + v4v.x*wv.x + v4v.y*wv.y + v4v.z*wv.z + v4v.w*wv.w;
            for (int off = 32; off > 0; off >>= 1) x += __shfl_down(x, off, 64);
            red[c] = x;
        }
        __syncthreads();
        if (lane == 0) {
#pragma unroll
            for (int c = 0; c < 4; c++) pw[w][c] = red[c];
        }
        __syncthreads();
        if (tid < 4) {
            float t = pw[0][tid] + pw[1][tid] + pw[2][tid] + pw[3][tid];
            int h = hp * 2 + (tid >> 1);
            int b = bs >> 11, s = bs & 2047;
            size_t o = ((size_t)(b * NHh + h)) * Ss + s;
            if (tid & 1) fg_out[o] = t + fgb[h];
            else         ig_out[o] = t + igb[h];
        }
    }
}

// ---------------------------------------------------------------------------
// Kernel 2: per-(b,h) scans (unchanged)
// ---------------------------------------------------------------------------
#define CHUNK 8
__global__ __launch_bounds__(256) void scan_kernel(
    const float* __restrict__ ig, const float* __restrict__ fg,
    float* __restrict__ a_out, float* __restrict__ M_out, float* __restrict__ nf_out)
{
    int bh = blockIdx.x;
    int tid = threadIdx.x;
    const float* igp = ig + (size_t)bh * Ss;
    const float* fgp = fg + (size_t)bh * Ss;
    int s0 = tid * CHUNK;

    float ls[CHUNK], cs[CHUNK];
    float tot = 0.f;
#pragma unroll
    for (int c = 0; c < CHUNK; c++) {
        float x = fgp[s0 + c];
        float l = fminf(x, 0.f) - log1pf(expf(-fabsf(x)));
        ls[c] = l; tot += l; cs[c] = tot;
    }
    __shared__ float sc[256];
    sc[tid] = tot; __syncthreads();
    for (int off = 1; off < 256; off <<= 1) {
        float add = (tid >= off) ? sc[tid - off] : 0.f;
        __syncthreads();
        sc[tid] += add;
        __syncthreads();
    }
    float excl = sc[tid] - tot;

    float av[CHUNK], pmax[CHUNK];
    float tmax = -INFINITY;
#pragma unroll
    for (int c = 0; c < CHUNK; c++) {
        float csf  = excl + cs[c];
        float csm1 = csf - ls[c];
        float a = igp[s0 + c] - csm1;
        av[c] = a;
        tmax = fmaxf(tmax, a);
        pmax[c] = tmax;
        cs[c] = csf;
    }
    __shared__ float sm[256];
    sm[tid] = tmax; __syncthreads();
    for (int off = 1; off < 256; off <<= 1) {
        float other = (tid >= off) ? sm[tid - off] : -INFINITY;
        __syncthreads();
        sm[tid] = fmaxf(sm[tid], other);
        __syncthreads();
    }
    float emax = (tid > 0) ? sm[tid - 1] : -INFINITY;
#pragma unroll
    for (int c = 0; c < CHUNK; c++) {
        float M = fmaxf(emax, pmax[c]);
        size_t o = (size_t)bh * Ss + s0 + c;
        a_out[o]  = av[c];
        M_out[o]  = M;
        nf_out[o] = expf(-cs[c] - M);
    }
}

// ---------------------------------------------------------------------------
// Kernel 2.5: pre-convert K and V tiles into bf16 LDS-image order (swizzle
// baked in). Image tile (bh,jt) = 1024 chunks x 16B, chunk index == LDS chunk.
// ---------------------------------------------------------------------------
__global__ __launch_bounds__(256) void prep_kernel(
    const float* __restrict__ kp, const float* __restrict__ vp,
    unsigned short* __restrict__ Kimg, unsigned short* __restrict__ Vimg)
{
    int bidx = blockIdx.x;          // bh*NJT + jt
    int bh = bidx >> 6, jt = bidx & 63;
    int b = bh >> 2, h = bh & 3;
    int J0 = jt * TJ;
    int tid = threadIdx.x;
    const size_t hoff = (size_t)h * DHh;
    unsigned short* Kt = Kimg + (size_t)bidx * 1024 * 8;
    unsigned short* Vt = Vimg + (size_t)bidx * 1024 * 8;

    // K: chunk(kR,cc) at kR*32 + (cc ^ (kR&7)), holds K[J0+kR][cc*8..+7]
    {
        int kR = tid >> 3, kc0 = tid & 7;
        const float* src = kp + ((size_t)(b * Ss + J0 + kR)) * Ee + hoff;
#pragma unroll
        for (int p = 0; p < 4; p++) {
            int cc = kc0 + 8 * p;
            float4 x0 = ((const float4*)(src + cc * 8))[0];
            float4 x1 = ((const float4*)(src + cc * 8))[1];
            u4v wv;
            wv.x = pkbf2(x0.x, x0.y); wv.y = pkbf2(x0.z, x0.w);
            wv.z = pkbf2(x1.x, x1.y); wv.w = pkbf2(x1.z, x1.w);
            *(u4v*)&Kt[(kR * 32 + (cc ^ (kR & 7))) * 8] = wv;
        }
    }
    // V^T: chunk(d,jc) at d*4 + (jc ^ ((d>>1)&3)), holds V[J0+jc*8+e][d], e=0..7
    {
        int vdp = tid & 127, vjb = tid >> 7;
        int d0 = vdp * 2;
#pragma unroll
        for (int p = 0; p < 2; p++) {
            int jc = vjb + 2 * p;
            const float* vbase = vp + ((size_t)(b * Ss + J0 + jc * 8)) * Ee + hoff + d0;
            float2 e0 = *(const float2*)(vbase);
            float2 e1 = *(const float2*)(vbase + Ee);
            float2 e2 = *(const float2*)(vbase + 2 * Ee);
            float2 e3 = *(const float2*)(vbase + 3 * Ee);
            float2 e4 = *(const float2*)(vbase + 4 * Ee);
            float2 e5 = *(const float2*)(vbase + 5 * Ee);
            float2 e6 = *(const float2*)(vbase + 6 * Ee);
            float2 e7 = *(const float2*)(vbase + 7 * Ee);
            int swz = jc ^ (vdp & 3);
            u4v w0, w1;
            w0.x = pkbf2(e0.x, e1.x); w0.y = pkbf2(e2.x, e3.x);
            w0.z = pkbf2(e4.x, e5.x); w0.w = pkbf2(e6.x, e7.x);
            w1.x = pkbf2(e0.y, e1.y); w1.y = pkbf2(e2.y, e3.y);
            w1.z = pkbf2(e4.y, e5.y); w1.w = pkbf2(e6.y, e7.y);
            *(u4v*)&Vt[(d0 * 4 + swz) * 8] = w0;
            *(u4v*)&Vt[((d0 + 1) * 4 + swz) * 8] = w1;
        }
    }
}

// ---------------------------------------------------------------------------
// Kernel 3: MFMA flash pass. IMG=true: stage via global_load_lds DMA from the
// pre-built images (no staging VALU/VGPRs). PARTS-way j-split per i-tile with
// constant per-CU-slot work (33 iters).
// ---------------------------------------------------------------------------
template<int PARTS, bool IMG>
__global__ __launch_bounds__(256, 4) void mlstm_main(
    const float* __restrict__ qp, const float* __restrict__ kp, const float* __restrict__ vp,
    const unsigned short* __restrict__ Kimg, const unsigned short* __restrict__ Vimg,
    const float* __restrict__ a_ws, const float* __restrict__ M_ws,
    float* __restrict__ outF, float* __restrict__ Hpart, float* __restrict__ rsbuf)
{
    int bidx = blockIdx.x;
    int bh, T, sg;
    if (PARTS == 1) {
        bh = bidx & 7; T = (NT2 - 1) - (bidx >> 3); sg = 0;
    } else {
        int qd = bidx >> 8, u = bidx & 255;
        bh = u & 7;
        int r = u >> 3;
        if (PARTS == 2) {
            T  = qd ? r : (31 - r);
            sg = r & 1;
        } else {  // PARTS == 4
            T  = (qd < 2) ? (31 - r) : r;
            sg = qd;
        }
    }
    int b = bh >> 2, h = bh & 3;
    int I0 = T * TI;
    int tid = threadIdx.x;

    const int tot = 2 * T + 2;
    const int jt_beg = (sg * tot) / PARTS;
    const int jt_end = ((sg + 1) * tot) / PARTS;
    const size_t hoff = (size_t)h * DHh;
    float* Hdst = (sg == 0) ? outF : (Hpart + (size_t)(sg - 1) * Bb * Ss * Ee);

    if (jt_beg >= jt_end) {      // empty segment: zero partials
        float4 z = {0.f, 0.f, 0.f, 0.f};
        for (int t = tid; t < TI * 64; t += 256) {
            int r2 = t >> 6, c = t & 63;
            *(float4*)(Hdst + ((size_t)(b * Ss + I0 + r2)) * Ee + hoff + 4 * c) = z;
        }
        if (tid < TI) rsbuf[(size_t)sg * BH * Ss + (size_t)bh * Ss + I0 + tid] = 0.f;
        return;
    }

    // Swizzled chunk layouts (chunk = 16B = 8 bf16):
    //  KF (32 j-rows x 32 cc):  chunk(row,cc) at row*32 + (cc ^ (row&7))
    //  VF (256 d-rows x 4 jc):  chunk(d,jc)  at d*4 + (jc ^ ((d>>1)&3))
    //  PF (64 i-rows x 4 kb):   chunk(i,kb)  at i*4 + (kb ^ ((i>>1)&3))
    __shared__ unsigned short KF[1024 * 8];   // 16 KB
    __shared__ unsigned short VF[1024 * 8];   // 16 KB
    __shared__ unsigned short PF[256 * 8];    //  4 KB
    __shared__ float a_s[TJ];
    __shared__ float rs_s[TI];

    const int iq   = tid >> 6;       // wave = i-quarter
    const int lane = tid & 63;
    const int lm = lane & 15, q4 = lane >> 4;
    const int m5 = lane & 31, hl = lane >> 5;

    // ---- Q fragments in registers (B-operand of S^T = K·Q^T) ----
    s8v qf[8];
    {
        const float* qrow = qp + ((size_t)(b * Ss + I0 + iq * 16 + lm)) * Ee + hoff;
#pragma unroll
        for (int ks = 0; ks < 8; ks++) {
            const float4* p = (const float4*)(qrow + ks * 32 + q4 * 8);
            float4 x0 = p[0], x1 = p[1];
            union { s8v v; unsigned u[4]; } r;
            r.u[0] = pkbf2(x0.x, x0.y);
            r.u[1] = pkbf2(x0.z, x0.w);
            r.u[2] = pkbf2(x1.x, x1.y);
            r.u[3] = pkbf2(x1.z, x1.w);
            qf[ks] = r.v;
        }
    }
    const int  i_row = I0 + iq * 16 + lm;
    const float Mi = M_ws[(size_t)bh * Ss + i_row];

    f16v acc[4];
#pragma unroll
    for (int t = 0; t < 4; t++)
#pragma unroll
        for (int i = 0; i < 16; i++) acc[t][i] = 0.f;
    float rs_acc = 0.f;

    const float inv_sqrt_dh = 0.0625f;
    const int kR  = tid >> 3, kc0 = tid & 7;              // inline K staging role
    const int vdp = tid & 127, vjb = tid >> 7;            // inline V staging role

    for (int jt = jt_beg; jt < jt_end; jt++) {
        const int J0 = jt * TJ;
        __syncthreads();   // prior iteration's MFMA reads done before overwrite

        if (IMG) {
            const unsigned short* Kt = Kimg + ((size_t)(bh * NJT + jt) * 1024) * 8;
            const unsigned short* Vt = Vimg + ((size_t)(bh * NJT + jt) * 1024) * 8;
#pragma unroll
            for (int p = 0; p < 4; p++) {
                int cbase = (iq * 4 + p) * 64;
                async16(Kt + (size_t)(cbase + lane) * 8, &KF[cbase * 8]);
                async16(Vt + (size_t)(cbase + lane) * 8, &VF[cbase * 8]);
            }
        } else {
            // ---- inline K staging ----
            const float* src = kp + ((size_t)(b * Ss + J0 + kR)) * Ee + hoff;
#pragma unroll
            for (int p = 0; p < 4; p++) {
                int cc = kc0 + 8 * p;
                float4 x0 = ((const float4*)(src + cc * 8))[0];
                float4 x1 = ((const float4*)(src + cc * 8))[1];
                u4v wv;
                wv.x = pkbf2(x0.x, x0.y); wv.y = pkbf2(x0.z, x0.w);
                wv.z = pkbf2(x1.x, x1.y); wv.w = pkbf2(x1.z, x1.w);
                *(u4v*)&KF[(kR * 32 + (cc ^ (kR & 7))) * 8] = wv;
            }
            // ---- inline V^T staging ----
            int d0 = vdp * 2;
#pragma unroll
            for (int p = 0; p < 2; p++) {
                int jc = vjb + 2 * p;
                const float* vbase = vp + ((size_t)(b * Ss + J0 + jc * 8)) * Ee + hoff + d0;
                float2 e0 = *(const float2*)(vbase);
                float2 e1 = *(const float2*)(vbase + Ee);
                float2 e2 = *(const float2*)(vbase + 2 * Ee);
                float2 e3 = *(const float2*)(vbase + 3 * Ee);
                float2 e4 = *(const float2*)(vbase + 4 * Ee);
                float2 e5 = *(const float2*)(vbase + 5 * Ee);
                float2 e6 = *(const float2*)(vbase + 6 * Ee);
                float2 e7 = *(const float2*)(vbase + 7 * Ee);
                int swz = jc ^ (vdp & 3);
                u4v w0, w1;
                w0.x = pkbf2(e0.x, e1.x); w0.y = pkbf2(e2.x, e3.x);
                w0.z = pkbf2(e4.x, e5.x); w0.w = pkbf2(e6.x, e7.x);
                w1.x = pkbf2(e0.y, e1.y); w1.y = pkbf2(e2.y, e3.y);
                w1.z = pkbf2(e4.y, e5.y); w1.w = pkbf2(e6.y, e7.y);
                *(u4v*)&VF[(d0 * 4 + swz) * 8] = w0;
                *(u4v*)&VF[((d0 + 1) * 4 + swz) * 8] = w1;
            }
        }
        if (tid < TJ) a_s[tid] = a_ws[(size_t)bh * Ss + J0 + tid];
        __syncthreads();   // drains vmcnt (incl. global_load_lds) before reads

        // ---- QK: S^T [32j x 16i] per wave via mfma 16x16x32 ----
        f4v c0 = {0.f, 0.f, 0.f, 0.f}, c1 = c0;
#pragma unroll
        for (int ks = 0; ks < 8; ks++) {
            int swzk = ((ks * 4 + q4) ^ (lm & 7)) * 8;
            s8v af0 = *(const s8v*)&KF[(lm * 32) * 8 + swzk];
            s8v af1 = *(const s8v*)&KF[((16 + lm) * 32) * 8 + swzk];
            c0 = __builtin_amdgcn_mfma_f32_16x16x32_bf16(af0, qf[ks], c0, 0, 0, 0);
            c1 = __builtin_amdgcn_mfma_f32_16x16x32_bf16(af1, qf[ks], c1, 0, 0, 0);
        }
        // decay + mask + pack P into PF (swizzled), accumulate signed rowsum
        {
            float rsum = 0.f;
#pragma unroll
            for (int t = 0; t < 2; t++) {
                const f4v cc = t ? c1 : c0;
                const int jb = t * 16 + q4 * 4;
                float p[4];
#pragma unroll
                for (int r = 0; r < 4; r++) {
                    int jg = J0 + jb + r;
                    float pv = 0.f;
                    if (jg <= i_row) pv = cc[r] * inv_sqrt_dh * __expf(a_s[jb + r] - Mi);
                    p[r] = pv; rsum += pv;
                }
                u2v pwv;
                pwv.x = pkbf2(p[0], p[1]);
                pwv.y = pkbf2(p[2], p[3]);
                int i = iq * 16 + lm;
                int kb = t * 2 + (q4 >> 1);
                *(u2v*)&PF[(i * 4 + (kb ^ ((i >> 1) & 3))) * 8 + (q4 & 1) * 4] = pwv;
            }
            rsum += __shfl_xor(rsum, 16);
            rsum += __shfl_xor(rsum, 32);
            rs_acc += rsum;
        }
        __syncthreads();

        // ---- PV: H[64 x 256] += P[64 x 32] · V[32 x 256] via mfma 32x32x16 ----
#pragma unroll
        for (int ks2 = 0; ks2 < 2; ks2++) {
            int swz2 = ((ks2 * 2 + hl) ^ ((m5 >> 1) & 3)) * 8;
            s8v pa0 = *(const s8v*)&PF[(m5 * 4) * 8 + swz2];
            s8v pa1 = *(const s8v*)&PF[((32 + m5) * 4) * 8 + swz2];
            s8v vb0 = *(const s8v*)&VF[((iq * 32 + m5) * 4) * 8 + swz2];
            s8v vb1 = *(const s8v*)&VF[(((iq + 4) * 32 + m5) * 4) * 8 + swz2];
            acc[0] = __builtin_amdgcn_mfma_f32_32x32x16_bf16(pa0, vb0, acc[0], 0, 0, 0);
            acc[1] = __builtin_amdgcn_mfma_f32_32x32x16_bf16(pa0, vb1, acc[1], 0, 0, 0);
            acc[2] = __builtin_amdgcn_mfma_f32_32x32x16_bf16(pa1, vb0, acc[2], 0, 0, 0);
            acc[3] = __builtin_amdgcn_mfma_f32_32x32x16_bf16(pa1, vb1, acc[3], 0, 0, 0);
        }
    }

    // ---- epilogue: rowsums + raw fp32 partial H straight from accs ----
    if (q4 == 0) rs_s[iq * 16 + lm] = rs_acc;
    __syncthreads();
    if (tid < TI)
        rsbuf[(size_t)sg * BH * Ss + (size_t)bh * Ss + I0 + tid] = rs_s[tid];

#pragma unroll
    for (int im = 0; im < 2; im++)
#pragma unroll
        for (int ns = 0; ns < 2; ns++) {
            const f16v av = acc[im * 2 + ns];
            const int col = (iq + 4 * ns) * 32 + m5;
#pragma unroll
            for (int r = 0; r < 16; r++) {
                int row = I0 + im * 32 + (r & 3) + 8 * (r >> 2) + 4 * hl;
                Hdst[((size_t)(b * Ss + row)) * Ee + hoff + col] = av[r];
            }
        }
}

// ---------------------------------------------------------------------------
// Kernel 4: combine PARTS partials, normalize, group-norm. 1 wave per row.
// ---------------------------------------------------------------------------
template<int PARTS>
__global__ __launch_bounds__(256) void combine_kernel(
    const float* __restrict__ Hb, const float* __restrict__ rsbuf,
    const float* __restrict__ nf_ws, const float* __restrict__ out_w,
    float* __restrict__ outF)
{
    int rid = blockIdx.x * 4 + (threadIdx.x >> 6);
    int lane = threadIdx.x & 63;
    int bh = rid >> 11, s = rid & 2047;
    int b = bh >> 2, h = bh & 3;
    size_t base = ((size_t)(b * Ss + s)) * Ee + (size_t)h * DHh + lane * 4;
    float4 ha = *(const float4*)(outF + base);
    float rs = rsbuf[(size_t)bh * Ss + s];
#pragma unroll
    for (int k = 1; k < PARTS; k++) {
        float4 hb = *(const float4*)(Hb + (size_t)(k - 1) * Bb * Ss * Ee + base);
        ha.x += hb.x; ha.y += hb.y; ha.z += hb.z; ha.w += hb.w;
        rs += rsbuf[(size_t)k * BH * Ss + (size_t)bh * Ss + s];
    }
    float nfv = nf_ws[(size_t)bh * Ss + s];
    float invn = 1.f / (fmaxf(fabsf(rs), nfv) + 1e-8f);
    float4 x;
    x.x = ha.x * invn; x.y = ha.y * invn; x.z = ha.z * invn; x.w = ha.w * invn;
    float sx = x.x + x.y + x.z + x.w;
    float sq = x.x*x.x + x.y*x.y + x.z*x.z + x.w*x.w;
#pragma unroll
    for (int off = 1; off < 64; off <<= 1) {
        sx += __shfl_xor(sx, off);
        sq += __shfl_xor(sq, off);
    }
    float mean = sx * (1.f / DHh);
    float var  = sq * (1.f / DHh) - mean * mean;
    float rstd = rsqrtf(var + 1e-5f);
    float4 w4 = *(const float4*)(out_w + (size_t)h * DHh + lane * 4);
    float4 o;
    o.x = (x.x - mean) * rstd * (1.f + w4.x);
    o.y = (x.y - mean) * rstd * (1.f + w4.y);
    o.z = (x.z - mean) * rstd * (1.f + w4.z);
    o.w = (x.w - mean) * rstd * (1.f + w4.w);
    *(float4*)(outF + base) = o;
}

// ---------------------------------------------------------------------------
extern "C" void kernel_launch(void* const* d_in, const int* in_sizes, int n_in,
                              void* d_out, int out_size, void* d_ws, size_t ws_size,
                              hipStream_t stream) {
    const float* q   = (const float*)d_in[0];
    const float* k   = (const float*)d_in[1];
    const float* v   = (const float*)d_in[2];
    const float* igw = (const float*)d_in[3];
    const float* igb = (const float*)d_in[4];
    const float* fgw = (const float*)d_in[5];
    const float* fgb = (const float*)d_in[6];
    const float* ow  = (const float*)d_in[7];
    float* out = (float*)d_out;

    float* ws = (float*)d_ws;
    float* ig = ws;                     // BH*S floats each
    float* fg = ws + 16384;
    float* aa = ws + 32768;
    float* MM = ws + 49152;
    float* nf = ws + 65536;
    float* rsb = ws + 81920;            // up to 4 * BH * S floats = 65536
    const size_t base_f = 81920 + 65536;            // = 147456 floats (589824 B)
    unsigned short* KimgP = (unsigned short*)(ws + base_f);
    const size_t img_u = (size_t)BH * NJT * 1024 * 8;        // 4M ushorts = 8 MB
    unsigned short* VimgP = KimgP + img_u;
    float* HpartImg = (float*)(VimgP + img_u);               // after images
    float* HpartRaw = ws + base_f;                           // no-image layout
    const size_t HP = (size_t)Bb * Ss * Ee;                  // 4M floats = 16 MB

    const size_t need4  = base_f * 4 + 2 * img_u * 2 + 3 * HP * 4;   // ~65.6 MB
    const size_t need2i = base_f * 4 + 2 * img_u * 2 + 1 * HP * 4;   // ~33.6 MB
    const size_t need2  = base_f * 4 + 1 * HP * 4;                   // ~17.4 MB

    gates_kernel<<<512, 256, 0, stream>>>(q, k, v, igw, igb, fgw, fgb, ig, fg);
    scan_kernel<<<BH, 256, 0, stream>>>(ig, fg, aa, MM, nf);

    if (ws_size >= need4) {
        prep_kernel<<<BH * NJT, 256, 0, stream>>>(k, v, KimgP, VimgP);
        mlstm_main<4, true><<<1024, 256, 0, stream>>>(q, k, v, KimgP, VimgP, aa, MM,
                                                      out, HpartImg, rsb);
        combine_kernel<4><<<BH * Ss / 4, 256, 0, stream>>>(HpartImg, rsb, nf, ow, out);
    } else if (ws_size >= need2i) {
        prep_kernel<<<BH * NJT, 256, 0, stream>>>(k, v, KimgP, VimgP);
        mlstm_main<2, true><<<512, 256, 0, stream>>>(q, k, v, KimgP, VimgP, aa, MM,
                                                     out, HpartImg, rsb);
        combine_kernel<2><<<BH * Ss / 4, 256, 0, stream>>>(HpartImg, rsb, nf, ow, out);
    } else if (ws_size >= need2) {
        mlstm_main<2, false><<<512, 256, 0, stream>>>(q, k, v, nullptr, nullptr, aa, MM,
                                                      out, HpartRaw, rsb);
        combine_kernel<2><<<BH * Ss / 4, 256, 0, stream>>>(HpartRaw, rsb, nf, ow, out);
    } else {
        mlstm_main<1, false><<<256, 256, 0, stream>>>(q, k, v, nullptr, nullptr, aa, MM,
                                                      out, HpartRaw, rsb);
        combine_kernel<1><<<BH * Ss / 4, 256, 0, stream>>>(HpartRaw, rsb, nf, ow, out);
    }
}

// Round 8
// 199.793 us; speedup vs baseline: 1.5126x; 1.2350x over previous
//
#include <hip/hip_runtime.h>
#include <hip/hip_bf16.h>
#include <math.h>

// Problem constants: B=2, S=2048, E=1024, NH=4, DH=256
#define Bb  2
#define Ss  2048
#define Ee  1024
#define NHh 4
#define DHh 256
#define BH  (Bb*NHh)      // 8
#define TI  64            // i-rows per block
#define TJ  32            // j-cols per iteration
#define NT2 (Ss/TI)       // 32 i-tiles per bh
#define NJT (Ss/TJ)       // 64 j-tiles per bh

typedef short        s8v   __attribute__((ext_vector_type(8)));   // 8 bf16 (A/B frag)
typedef float        f4v   __attribute__((ext_vector_type(4)));   // 16x16 acc
typedef float        f16v  __attribute__((ext_vector_type(16)));  // 32x32 acc
typedef unsigned int u4v   __attribute__((ext_vector_type(4)));   // 16B LDS write
typedef unsigned int u2v   __attribute__((ext_vector_type(2)));   // 8B LDS write

// fp32 pair -> packed bf16x2 via HW v_cvt_pk_bf16_f32 (a = low 16)
__device__ inline unsigned pkbf2(float a, float b) {
    __hip_bfloat162 h2 = __float22bfloat162_rn(float2{a, b});
    unsigned u;
    __builtin_memcpy(&u, &h2, 4);
    return u;
}

// async 16B global->LDS DMA; lds arg must be wave-uniform (HW adds lane*16)
__device__ inline void async16(const void* g, void* l) {
    __builtin_amdgcn_global_load_lds(
        (const __attribute__((address_space(1))) void*)g,
        (__attribute__((address_space(3))) void*)l, 16, 0, 0);
}

// ---------------------------------------------------------------------------
// Kernel 1 (fused): blocks 0..511 = gates (weights LDS-staged, 16 rows x 2
// heads each); blocks 512..1023 = prep (K/V -> swizzled bf16 LDS images).
// ---------------------------------------------------------------------------
__global__ __launch_bounds__(256) void gates_prep_kernel(
    const float* __restrict__ q, const float* __restrict__ k, const float* __restrict__ v,
    const float* __restrict__ igw, const float* __restrict__ igb,
    const float* __restrict__ fgw, const float* __restrict__ fgb,
    float* __restrict__ ig_out, float* __restrict__ fg_out,
    unsigned short* __restrict__ Kimg, unsigned short* __restrict__ Vimg)
{
    int bidx = blockIdx.x;
    int tid = threadIdx.x;

    if (bidx >= 512) {               // ---------------- prep path ----------------
        int pidx = bidx - 512;       // bh*NJT + jt ... NJT=64 -> pidx = bh*64+jt
        int bh = pidx >> 6, jt = pidx & 63;
        int b = bh >> 2, h = bh & 3;
        int J0 = jt * TJ;
        const size_t hoff = (size_t)h * DHh;
        unsigned short* Kt = Kimg + (size_t)pidx * 1024 * 8;
        unsigned short* Vt = Vimg + (size_t)pidx * 1024 * 8;

        // K: chunk(kR,cc) at kR*32 + (cc ^ (kR&7)), holds K[J0+kR][cc*8..+7]
        {
            int kR = tid >> 3, kc0 = tid & 7;
            const float* src = k + ((size_t)(b * Ss + J0 + kR)) * Ee + hoff;
#pragma unroll
            for (int p = 0; p < 4; p++) {
                int cc = kc0 + 8 * p;
                float4 x0 = ((const float4*)(src + cc * 8))[0];
                float4 x1 = ((const float4*)(src + cc * 8))[1];
                u4v wv;
                wv.x = pkbf2(x0.x, x0.y); wv.y = pkbf2(x0.z, x0.w);
                wv.z = pkbf2(x1.x, x1.y); wv.w = pkbf2(x1.z, x1.w);
                *(u4v*)&Kt[(kR * 32 + (cc ^ (kR & 7))) * 8] = wv;
            }
        }
        // V^T: chunk(d,jc) at d*4 + (jc ^ ((d>>1)&3)), holds V[J0+jc*8+e][d]
        {
            int vdp = tid & 127, vjb = tid >> 7;
            int d0 = vdp * 2;
#pragma unroll
            for (int p = 0; p < 2; p++) {
                int jc = vjb + 2 * p;
                const float* vbase = v + ((size_t)(b * Ss + J0 + jc * 8)) * Ee + hoff + d0;
                float2 e0 = *(const float2*)(vbase);
                float2 e1 = *(const float2*)(vbase + Ee);
                float2 e2 = *(const float2*)(vbase + 2 * Ee);
                float2 e3 = *(const float2*)(vbase + 3 * Ee);
                float2 e4 = *(const float2*)(vbase + 4 * Ee);
                float2 e5 = *(const float2*)(vbase + 5 * Ee);
                float2 e6 = *(const float2*)(vbase + 6 * Ee);
                float2 e7 = *(const float2*)(vbase + 7 * Ee);
                int swz = jc ^ (vdp & 3);
                u4v w0, w1;
                w0.x = pkbf2(e0.x, e1.x); w0.y = pkbf2(e2.x, e3.x);
                w0.z = pkbf2(e4.x, e5.x); w0.w = pkbf2(e6.x, e7.x);
                w1.x = pkbf2(e0.y, e1.y); w1.y = pkbf2(e2.y, e3.y);
                w1.z = pkbf2(e4.y, e5.y); w1.w = pkbf2(e6.y, e7.y);
                *(u4v*)&Vt[(d0 * 4 + swz) * 8] = w0;
                *(u4v*)&Vt[((d0 + 1) * 4 + swz) * 8] = w1;
            }
        }
        return;
    }

    // ---------------- gates path ----------------
    int sc = bidx >> 1, hp = bidx & 1;
    __shared__ float wl[4][3072];          // 48 KB
    __shared__ float pw[4][4];

#pragma unroll
    for (int c = 0; c < 4; c++) {
        int h = hp * 2 + (c >> 1);
        const float* src = ((c & 1) ? fgw : igw) + (size_t)h * 3 * Ee;
        for (int idx = tid * 4; idx < 3 * Ee; idx += 1024)
            *(float4*)&wl[c][idx] = *(const float4*)(src + idx);
    }
    __syncthreads();

    int c4 = tid * 4;
    int w = tid >> 6, lane = tid & 63;

    for (int ss = 0; ss < 16; ss++) {
        int bs = sc * 16 + ss;
        float4 q4v = *(const float4*)(q + (size_t)bs * Ee + c4);
        float4 k4v = *(const float4*)(k + (size_t)bs * Ee + c4);
        float4 v4v = *(const float4*)(v + (size_t)bs * Ee + c4);
        float red[4];
#pragma unroll
        for (int c = 0; c < 4; c++) {
            const float* wc = wl[c];
            float4 wq = *(const float4*)&wc[c4];
            float4 wk = *(const float4*)&wc[Ee + c4];
            float4 wv = *(const float4*)&wc[2 * Ee + c4];
            float x = q4v.x*wq.x + q4v.y*wq.y + q4v.z*wq.z + q4v.w*wq.w
                    + k4v.x*wk.x + k4v.y*wk.y + k4v.z*wk.z + k4v.w*wk.w
                    + v4v.x*wv.x + v4v.y*wv.y + v4v.z*wv.z + v4v.w*wv.w;
            for (int off = 32; off > 0; off >>= 1) x += __shfl_down(x, off, 64);
            red[c] = x;
        }
        __syncthreads();
        if (lane == 0) {
#pragma unroll
            for (int c = 0; c < 4; c++) pw[w][c] = red[c];
        }
        __syncthreads();
        if (tid < 4) {
            float t = pw[0][tid] + pw[1][tid] + pw[2][tid] + pw[3][tid];
            int h = hp * 2 + (tid >> 1);
            int b = bs >> 11, s = bs & 2047;
            size_t o = ((size_t)(b * NHh + h)) * Ss + s;
            if (tid & 1) fg_out[o] = t + fgb[h];
            else         ig_out[o] = t + igb[h];
        }
    }
}

// ---------------------------------------------------------------------------
// Kernel 2: per-(b,h) scans (unchanged)
// ---------------------------------------------------------------------------
#define CHUNK 8
__global__ __launch_bounds__(256) void scan_kernel(
    const float* __restrict__ ig, const float* __restrict__ fg,
    float* __restrict__ a_out, float* __restrict__ M_out, float* __restrict__ nf_out)
{
    int bh = blockIdx.x;
    int tid = threadIdx.x;
    const float* igp = ig + (size_t)bh * Ss;
    const float* fgp = fg + (size_t)bh * Ss;
    int s0 = tid * CHUNK;

    float ls[CHUNK], cs[CHUNK];
    float tot = 0.f;
#pragma unroll
    for (int c = 0; c < CHUNK; c++) {
        float x = fgp[s0 + c];
        float l = fminf(x, 0.f) - log1pf(expf(-fabsf(x)));
        ls[c] = l; tot += l; cs[c] = tot;
    }
    __shared__ float sc[256];
    sc[tid] = tot; __syncthreads();
    for (int off = 1; off < 256; off <<= 1) {
        float add = (tid >= off) ? sc[tid - off] : 0.f;
        __syncthreads();
        sc[tid] += add;
        __syncthreads();
    }
    float excl = sc[tid] - tot;

    float av[CHUNK], pmax[CHUNK];
    float tmax = -INFINITY;
#pragma unroll
    for (int c = 0; c < CHUNK; c++) {
        float csf  = excl + cs[c];
        float csm1 = csf - ls[c];
        float a = igp[s0 + c] - csm1;
        av[c] = a;
        tmax = fmaxf(tmax, a);
        pmax[c] = tmax;
        cs[c] = csf;
    }
    __shared__ float sm[256];
    sm[tid] = tmax; __syncthreads();
    for (int off = 1; off < 256; off <<= 1) {
        float other = (tid >= off) ? sm[tid - off] : -INFINITY;
        __syncthreads();
        sm[tid] = fmaxf(sm[tid], other);
        __syncthreads();
    }
    float emax = (tid > 0) ? sm[tid - 1] : -INFINITY;
#pragma unroll
    for (int c = 0; c < CHUNK; c++) {
        float M = fmaxf(emax, pmax[c]);
        size_t o = (size_t)bh * Ss + s0 + c;
        a_out[o]  = av[c];
        M_out[o]  = M;
        nf_out[o] = expf(-cs[c] - M);
    }
}

// ---------------------------------------------------------------------------
// Kernel 3 (main path): double-buffered DMA flash pass, ONE barrier per iter.
// PV retiled to 16x mfma 16x16x32 per wave: each wave consumes only its own
// P rows -> P round-trips through wave-private LDS (no cross-wave barrier).
// ---------------------------------------------------------------------------
__global__ __launch_bounds__(256, 2) void mlstm_dbuf(
    const float* __restrict__ qp,
    const unsigned short* __restrict__ Kimg, const unsigned short* __restrict__ Vimg,
    const float* __restrict__ a_ws, const float* __restrict__ M_ws,
    float* __restrict__ outF, float* __restrict__ Hpart, float* __restrict__ rsbuf)
{
    // PARTS=4 balanced mapping (per-CU slot sums to ~33 iters)
    int bidx = blockIdx.x;
    int qd = bidx >> 8, u = bidx & 255;
    int bh = u & 7;
    int r  = u >> 3;
    int T  = (qd < 2) ? (31 - r) : r;
    int sg = qd;
    int b = bh >> 2, h = bh & 3;
    int I0 = T * TI;
    int tid = threadIdx.x;

    const int tot = 2 * T + 2;
    const int jt_beg = (sg * tot) / 4;
    const int jt_end = ((sg + 1) * tot) / 4;
    const size_t hoff = (size_t)h * DHh;
    float* Hdst = (sg == 0) ? outF : (Hpart + (size_t)(sg - 1) * Bb * Ss * Ee);

    if (jt_beg >= jt_end) {      // empty segment: zero partials
        float4 z = {0.f, 0.f, 0.f, 0.f};
        for (int t = tid; t < TI * 64; t += 256) {
            int r2 = t >> 6, c = t & 63;
            *(float4*)(Hdst + ((size_t)(b * Ss + I0 + r2)) * Ee + hoff + 4 * c) = z;
        }
        if (tid < TI) rsbuf[(size_t)sg * BH * Ss + (size_t)bh * Ss + I0 + tid] = 0.f;
        return;
    }

    __shared__ unsigned short KF[2][1024 * 8];   // 2 x 16 KB
    __shared__ unsigned short VF[2][1024 * 8];   // 2 x 16 KB
    __shared__ unsigned short PF[256 * 8];       // 4 KB (wave-private quarters)
    __shared__ float a_s[2][TJ];
    __shared__ float rs_s[TI];

    const int iq   = tid >> 6;       // wave = i-quarter
    const int lane = tid & 63;
    const int lm = lane & 15, q4 = lane >> 4;

    // ---- Q fragments in registers (B-operand of S^T = K·Q^T) ----
    s8v qf[8];
    {
        const float* qrow = qp + ((size_t)(b * Ss + I0 + iq * 16 + lm)) * Ee + hoff;
#pragma unroll
        for (int ks = 0; ks < 8; ks++) {
            const float4* p = (const float4*)(qrow + ks * 32 + q4 * 8);
            float4 x0 = p[0], x1 = p[1];
            union { s8v v; unsigned u[4]; } rr;
            rr.u[0] = pkbf2(x0.x, x0.y);
            rr.u[1] = pkbf2(x0.z, x0.w);
            rr.u[2] = pkbf2(x1.x, x1.y);
            rr.u[3] = pkbf2(x1.z, x1.w);
            qf[ks] = rr.v;
        }
    }
    const int  i_row = I0 + iq * 16 + lm;
    const float Mi = M_ws[(size_t)bh * Ss + i_row];

    f4v acc[16];                      // H[i=iq*16+q4*4+rr][d=db*16+lm]
#pragma unroll
    for (int t = 0; t < 16; t++) { acc[t][0]=0.f; acc[t][1]=0.f; acc[t][2]=0.f; acc[t][3]=0.f; }
    float rs_acc = 0.f;
    const float inv_sqrt_dh = 0.0625f;

    const unsigned short* Kb = Kimg + (size_t)(bh * NJT) * 1024 * 8;
    const unsigned short* Vb = Vimg + (size_t)(bh * NJT) * 1024 * 8;

    // prologue: fill buffer 0 for jt_beg
    {
        const unsigned short* Kt = Kb + (size_t)jt_beg * 1024 * 8;
        const unsigned short* Vt = Vb + (size_t)jt_beg * 1024 * 8;
#pragma unroll
        for (int p = 0; p < 4; p++) {
            int cbase = (iq * 4 + p) * 64;
            async16(Kt + (size_t)(cbase + lane) * 8, &KF[0][cbase * 8]);
            async16(Vt + (size_t)(cbase + lane) * 8, &VF[0][cbase * 8]);
        }
        if (tid < TJ) a_s[0][tid] = a_ws[(size_t)bh * Ss + jt_beg * TJ + tid];
    }

    int cur = 0;
    for (int jt = jt_beg; jt < jt_end; jt++, cur ^= 1) {
        __syncthreads();   // DMA(jt->cur) done (issued one full iter ago); prev reads of buf[1-cur] done

        if (jt + 1 < jt_end) {     // prefetch next tile into the other buffer
            const unsigned short* Kt = Kb + (size_t)(jt + 1) * 1024 * 8;
            const unsigned short* Vt = Vb + (size_t)(jt + 1) * 1024 * 8;
#pragma unroll
            for (int p = 0; p < 4; p++) {
                int cbase = (iq * 4 + p) * 64;
                async16(Kt + (size_t)(cbase + lane) * 8, &KF[cur ^ 1][cbase * 8]);
                async16(Vt + (size_t)(cbase + lane) * 8, &VF[cur ^ 1][cbase * 8]);
            }
            if (tid < TJ) a_s[cur ^ 1][tid] = a_ws[(size_t)bh * Ss + (jt + 1) * TJ + tid];
        }
        const int J0 = jt * TJ;

        // ---- QK: S^T [32j x 16i] per wave via mfma 16x16x32 ----
        f4v c0 = {0.f, 0.f, 0.f, 0.f}, c1 = c0;
#pragma unroll
        for (int ks = 0; ks < 8; ks++) {
            int swzk = ((ks * 4 + q4) ^ (lm & 7)) * 8;
            s8v af0 = *(const s8v*)&KF[cur][(lm * 32) * 8 + swzk];
            s8v af1 = *(const s8v*)&KF[cur][((16 + lm) * 32) * 8 + swzk];
            c0 = __builtin_amdgcn_mfma_f32_16x16x32_bf16(af0, qf[ks], c0, 0, 0, 0);
            c1 = __builtin_amdgcn_mfma_f32_16x16x32_bf16(af1, qf[ks], c1, 0, 0, 0);
        }
        // decay + mask + rowsum + pack P into wave-private PF quarter
        {
            float rsum = 0.f;
#pragma unroll
            for (int t = 0; t < 2; t++) {
                const f4v cc = t ? c1 : c0;
                const int jb = t * 16 + q4 * 4;
                float p[4];
#pragma unroll
                for (int rr = 0; rr < 4; rr++) {
                    int jg = J0 + jb + rr;
                    float pv = 0.f;
                    if (jg <= i_row) pv = cc[rr] * inv_sqrt_dh * __expf(a_s[cur][jb + rr] - Mi);
                    p[rr] = pv; rsum += pv;
                }
                u2v pwv;
                pwv.x = pkbf2(p[0], p[1]);
                pwv.y = pkbf2(p[2], p[3]);
                int kb = t * 2 + (q4 >> 1);
                *(u2v*)&PF[(iq * 64 + lm * 4 + (kb ^ (lm & 3))) * 8 + (q4 & 1) * 4] = pwv;
            }
            rsum += __shfl_xor(rsum, 16);
            rsum += __shfl_xor(rsum, 32);
            rs_acc += rsum;
        }
        // wave-private PF read-back in A-frag order (lgkmcnt-ordered, no barrier)
        s8v pa = *(const s8v*)&PF[(iq * 64 + lm * 4 + (q4 ^ (lm & 3))) * 8];

        // ---- PV: H[16i x 256d] += P[16 x 32] · V[32 x 256], 16x mfma 16x16x32 ----
#pragma unroll
        for (int db = 0; db < 16; db++) {
            int d = db * 16 + lm;
            s8v vb = *(const s8v*)&VF[cur][(d * 4 + (q4 ^ ((d >> 1) & 3))) * 8];
            acc[db] = __builtin_amdgcn_mfma_f32_16x16x32_bf16(pa, vb, acc[db], 0, 0, 0);
        }
    }

    // ---- epilogue: rowsums + raw fp32 partial H straight from accs ----
    if (q4 == 0) rs_s[iq * 16 + lm] = rs_acc;
    __syncthreads();
    if (tid < TI)
        rsbuf[(size_t)sg * BH * Ss + (size_t)bh * Ss + I0 + tid] = rs_s[tid];

#pragma unroll
    for (int rr = 0; rr < 4; rr++) {
        float* row = Hdst + ((size_t)(b * Ss + I0 + iq * 16 + q4 * 4 + rr)) * Ee + hoff + lm;
#pragma unroll
        for (int db = 0; db < 16; db++)
            row[db * 16] = acc[db][rr];
    }
}

// ---------------------------------------------------------------------------
// Kernel 3b (fallback, inline staging, 3-barrier): kept for small workspaces.
// ---------------------------------------------------------------------------
template<int PARTS>
__global__ __launch_bounds__(256, 4) void mlstm_fallback(
    const float* __restrict__ qp, const float* __restrict__ kp, const float* __restrict__ vp,
    const float* __restrict__ a_ws, const float* __restrict__ M_ws,
    float* __restrict__ outF, float* __restrict__ Hpart, float* __restrict__ rsbuf)
{
    int bidx = blockIdx.x;
    int bh, T, sg;
    if (PARTS == 1) {
        bh = bidx & 7; T = (NT2 - 1) - (bidx >> 3); sg = 0;
    } else {
        int qd = bidx >> 8, u = bidx & 255;
        bh = u & 7;
        int r = u >> 3;
        T  = qd ? r : (31 - r);
        sg = r & 1;
    }
    int b = bh >> 2, h = bh & 3;
    int I0 = T * TI;
    int tid = threadIdx.x;

    const int tot = 2 * T + 2;
    const int jt_beg = (sg * tot) / PARTS;
    const int jt_end = ((sg + 1) * tot) / PARTS;
    const size_t hoff = (size_t)h * DHh;
    float* Hdst = (sg == 0) ? outF : (Hpart + (size_t)(sg - 1) * Bb * Ss * Ee);

    if (jt_beg >= jt_end) {
        float4 z = {0.f, 0.f, 0.f, 0.f};
        for (int t = tid; t < TI * 64; t += 256) {
            int r2 = t >> 6, c = t & 63;
            *(float4*)(Hdst + ((size_t)(b * Ss + I0 + r2)) * Ee + hoff + 4 * c) = z;
        }
        if (tid < TI) rsbuf[(size_t)sg * BH * Ss + (size_t)bh * Ss + I0 + tid] = 0.f;
        return;
    }

    __shared__ unsigned short KF[1024 * 8];
    __shared__ unsigned short VF[1024 * 8];
    __shared__ unsigned short PF[256 * 8];
    __shared__ float a_s[TJ];
    __shared__ float rs_s[TI];

    const int iq   = tid >> 6;
    const int lane = tid & 63;
    const int lm = lane & 15, q4 = lane >> 4;
    const int m5 = lane & 31, hl = lane >> 5;

    s8v qf[8];
    {
        const float* qrow = qp + ((size_t)(b * Ss + I0 + iq * 16 + lm)) * Ee + hoff;
#pragma unroll
        for (int ks = 0; ks < 8; ks++) {
            const float4* p = (const float4*)(qrow + ks * 32 + q4 * 8);
            float4 x0 = p[0], x1 = p[1];
            union { s8v v; unsigned u[4]; } rr;
            rr.u[0] = pkbf2(x0.x, x0.y);
            rr.u[1] = pkbf2(x0.z, x0.w);
            rr.u[2] = pkbf2(x1.x, x1.y);
            rr.u[3] = pkbf2(x1.z, x1.w);
            qf[ks] = rr.v;
        }
    }
    const int  i_row = I0 + iq * 16 + lm;
    const float Mi = M_ws[(size_t)bh * Ss + i_row];

    f16v acc[4];
#pragma unroll
    for (int t = 0; t < 4; t++)
#pragma unroll
        for (int i = 0; i < 16; i++) acc[t][i] = 0.f;
    float rs_acc = 0.f;

    const float inv_sqrt_dh = 0.0625f;
    const int kR  = tid >> 3, kc0 = tid & 7;
    const int vdp = tid & 127, vjb = tid >> 7;

    for (int jt = jt_beg; jt < jt_end; jt++) {
        const int J0 = jt * TJ;
        __syncthreads();
        {
            const float* src = kp + ((size_t)(b * Ss + J0 + kR)) * Ee + hoff;
#pragma unroll
            for (int p = 0; p < 4; p++) {
                int cc = kc0 + 8 * p;
                float4 x0 = ((const float4*)(src + cc * 8))[0];
                float4 x1 = ((const float4*)(src + cc * 8))[1];
                u4v wv;
                wv.x = pkbf2(x0.x, x0.y); wv.y = pkbf2(x0.z, x0.w);
                wv.z = pkbf2(x1.x, x1.y); wv.w = pkbf2(x1.z, x1.w);
                *(u4v*)&KF[(kR * 32 + (cc ^ (kR & 7))) * 8] = wv;
            }
            int d0 = vdp * 2;
#pragma unroll
            for (int p = 0; p < 2; p++) {
                int jc = vjb + 2 * p;
                const float* vbase = vp + ((size_t)(b * Ss + J0 + jc * 8)) * Ee + hoff + d0;
                float2 e0 = *(const float2*)(vbase);
                float2 e1 = *(const float2*)(vbase + Ee);
                float2 e2 = *(const float2*)(vbase + 2 * Ee);
                float2 e3 = *(const float2*)(vbase + 3 * Ee);
                float2 e4 = *(const float2*)(vbase + 4 * Ee);
                float2 e5 = *(const float2*)(vbase + 5 * Ee);
                float2 e6 = *(const float2*)(vbase + 6 * Ee);
                float2 e7 = *(const float2*)(vbase + 7 * Ee);
                int swz = jc ^ (vdp & 3);
                u4v w0, w1;
                w0.x = pkbf2(e0.x, e1.x); w0.y = pkbf2(e2.x, e3.x);
                w0.z = pkbf2(e4.x, e5.x); w0.w = pkbf2(e6.x, e7.x);
                w1.x = pkbf2(e0.y, e1.y); w1.y = pkbf2(e2.y, e3.y);
                w1.z = pkbf2(e4.y, e5.y); w1.w = pkbf2(e6.y, e7.y);
                *(u4v*)&VF[(d0 * 4 + swz) * 8] = w0;
                *(u4v*)&VF[((d0 + 1) * 4 + swz) * 8] = w1;
            }
        }
        if (tid < TJ) a_s[tid] = a_ws[(size_t)bh * Ss + J0 + tid];
        __syncthreads();

        f4v c0 = {0.f, 0.f, 0.f, 0.f}, c1 = c0;
#pragma unroll
        for (int ks = 0; ks < 8; ks++) {
            int swzk = ((ks * 4 + q4) ^ (lm & 7)) * 8;
            s8v af0 = *(const s8v*)&KF[(lm * 32) * 8 + swzk];
            s8v af1 = *(const s8v*)&KF[((16 + lm) * 32) * 8 + swzk];
            c0 = __builtin_amdgcn_mfma_f32_16x16x32_bf16(af0, qf[ks], c0, 0, 0, 0);
            c1 = __builtin_amdgcn_mfma_f32_16x16x32_bf16(af1, qf[ks], c1, 0, 0, 0);
        }
        {
            float rsum = 0.f;
#pragma unroll
            for (int t = 0; t < 2; t++) {
                const f4v cc = t ? c1 : c0;
                const int jb = t * 16 + q4 * 4;
                float p[4];
#pragma unroll
                for (int rr = 0; rr < 4; rr++) {
                    int jg = J0 + jb + rr;
                    float pv = 0.f;
                    if (jg <= i_row) pv = cc[rr] * inv_sqrt_dh * __expf(a_s[jb + rr] - Mi);
                    p[rr] = pv; rsum += pv;
                }
                u2v pwv;
                pwv.x = pkbf2(p[0], p[1]);
                pwv.y = pkbf2(p[2], p[3]);
                int i = iq * 16 + lm;
                int kb = t * 2 + (q4 >> 1);
                *(u2v*)&PF[(i * 4 + (kb ^ ((i >> 1) & 3))) * 8 + (q4 & 1) * 4] = pwv;
            }
            rsum += __shfl_xor(rsum, 16);
            rsum += __shfl_xor(rsum, 32);
            rs_acc += rsum;
        }
        __syncthreads();

#pragma unroll
        for (int ks2 = 0; ks2 < 2; ks2++) {
            int swz2 = ((ks2 * 2 + hl) ^ ((m5 >> 1) & 3)) * 8;
            s8v pa0 = *(const s8v*)&PF[(m5 * 4) * 8 + swz2];
            s8v pa1 = *(const s8v*)&PF[((32 + m5) * 4) * 8 + swz2];
            s8v vb0 = *(const s8v*)&VF[((iq * 32 + m5) * 4) * 8 + swz2];
            s8v vb1 = *(const s8v*)&VF[(((iq + 4) * 32 + m5) * 4) * 8 + swz2];
            acc[0] = __builtin_amdgcn_mfma_f32_32x32x16_bf16(pa0, vb0, acc[0], 0, 0, 0);
            acc[1] = __builtin_amdgcn_mfma_f32_32x32x16_bf16(pa0, vb1, acc[1], 0, 0, 0);
            acc[2] = __builtin_amdgcn_mfma_f32_32x32x16_bf16(pa1, vb0, acc[2], 0, 0, 0);
            acc[3] = __builtin_amdgcn_mfma_f32_32x32x16_bf16(pa1, vb1, acc[3], 0, 0, 0);
        }
    }

    if (q4 == 0) rs_s[iq * 16 + lm] = rs_acc;
    __syncthreads();
    if (tid < TI)
        rsbuf[(size_t)sg * BH * Ss + (size_t)bh * Ss + I0 + tid] = rs_s[tid];

#pragma unroll
    for (int im = 0; im < 2; im++)
#pragma unroll
        for (int ns = 0; ns < 2; ns++) {
            const f16v av = acc[im * 2 + ns];
            const int col = (iq + 4 * ns) * 32 + m5;
#pragma unroll
            for (int rr = 0; rr < 16; rr++) {
                int row = I0 + im * 32 + (rr & 3) + 8 * (rr >> 2) + 4 * hl;
                Hdst[((size_t)(b * Ss + row)) * Ee + hoff + col] = av[rr];
            }
        }
}

// ---------------------------------------------------------------------------
// Kernel 4: combine PARTS partials, normalize, group-norm. 1 wave per row.
// ---------------------------------------------------------------------------
template<int PARTS>
__global__ __launch_bounds__(256) void combine_kernel(
    const float* __restrict__ Hb, const float* __restrict__ rsbuf,
    const float* __restrict__ nf_ws, const float* __restrict__ out_w,
    float* __restrict__ outF)
{
    int rid = blockIdx.x * 4 + (threadIdx.x >> 6);
    int lane = threadIdx.x & 63;
    int bh = rid >> 11, s = rid & 2047;
    int b = bh >> 2, h = bh & 3;
    size_t base = ((size_t)(b * Ss + s)) * Ee + (size_t)h * DHh + lane * 4;
    float4 ha = *(const float4*)(outF + base);
    float rs = rsbuf[(size_t)bh * Ss + s];
#pragma unroll
    for (int k = 1; k < PARTS; k++) {
        float4 hb = *(const float4*)(Hb + (size_t)(k - 1) * Bb * Ss * Ee + base);
        ha.x += hb.x; ha.y += hb.y; ha.z += hb.z; ha.w += hb.w;
        rs += rsbuf[(size_t)k * BH * Ss + (size_t)bh * Ss + s];
    }
    float nfv = nf_ws[(size_t)bh * Ss + s];
    float invn = 1.f / (fmaxf(fabsf(rs), nfv) + 1e-8f);
    float4 x;
    x.x = ha.x * invn; x.y = ha.y * invn; x.z = ha.z * invn; x.w = ha.w * invn;
    float sx = x.x + x.y + x.z + x.w;
    float sq = x.x*x.x + x.y*x.y + x.z*x.z + x.w*x.w;
#pragma unroll
    for (int off = 1; off < 64; off <<= 1) {
        sx += __shfl_xor(sx, off);
        sq += __shfl_xor(sq, off);
    }
    float mean = sx * (1.f / DHh);
    float var  = sq * (1.f / DHh) - mean * mean;
    float rstd = rsqrtf(var + 1e-5f);
    float4 w4 = *(const float4*)(out_w + (size_t)h * DHh + lane * 4);
    float4 o;
    o.x = (x.x - mean) * rstd * (1.f + w4.x);
    o.y = (x.y - mean) * rstd * (1.f + w4.y);
    o.z = (x.z - mean) * rstd * (1.f + w4.z);
    o.w = (x.w - mean) * rstd * (1.f + w4.w);
    *(float4*)(outF + base) = o;
}

// ---------------------------------------------------------------------------
extern "C" void kernel_launch(void* const* d_in, const int* in_sizes, int n_in,
                              void* d_out, int out_size, void* d_ws, size_t ws_size,
                              hipStream_t stream) {
    const float* q   = (const float*)d_in[0];
    const float* k   = (const float*)d_in[1];
    const float* v   = (const float*)d_in[2];
    const float* igw = (const float*)d_in[3];
    const float* igb = (const float*)d_in[4];
    const float* fgw = (const float*)d_in[5];
    const float* fgb = (const float*)d_in[6];
    const float* ow  = (const float*)d_in[7];
    float* out = (float*)d_out;

    float* ws = (float*)d_ws;
    float* ig = ws;                     // BH*S floats each
    float* fg = ws + 16384;
    float* aa = ws + 32768;
    float* MM = ws + 49152;
    float* nf = ws + 65536;
    float* rsb = ws + 81920;            // up to 4 * BH * S floats = 65536
    const size_t base_f = 81920 + 65536;            // 147456 floats
    unsigned short* KimgP = (unsigned short*)(ws + base_f);
    const size_t img_u = (size_t)BH * NJT * 1024 * 8;        // 8 MB each
    unsigned short* VimgP = KimgP + img_u;
    float* HpartImg = (float*)(VimgP + img_u);
    float* HpartRaw = ws + base_f;
    const size_t HP = (size_t)Bb * Ss * Ee;                  // 16 MB

    const size_t need4  = base_f * 4 + 2 * img_u * 2 + 3 * HP * 4;
    const size_t need2  = base_f * 4 + 1 * HP * 4;

    if (ws_size >= need4) {
        gates_prep_kernel<<<1024, 256, 0, stream>>>(q, k, v, igw, igb, fgw, fgb,
                                                    ig, fg, KimgP, VimgP);
        scan_kernel<<<BH, 256, 0, stream>>>(ig, fg, aa, MM, nf);
        mlstm_dbuf<<<1024, 256, 0, stream>>>(q, KimgP, VimgP, aa, MM,
                                             out, HpartImg, rsb);
        combine_kernel<4><<<BH * Ss / 4, 256, 0, stream>>>(HpartImg, rsb, nf, ow, out);
    } else if (ws_size >= need2) {
        gates_prep_kernel<<<512, 256, 0, stream>>>(q, k, v, igw, igb, fgw, fgb,
                                                   ig, fg, nullptr, nullptr);
        scan_kernel<<<BH, 256, 0, stream>>>(ig, fg, aa, MM, nf);
        mlstm_fallback<2><<<512, 256, 0, stream>>>(q, k, v, aa, MM, out, HpartRaw, rsb);
        combine_kernel<2><<<BH * Ss / 4, 256, 0, stream>>>(HpartRaw, rsb, nf, ow, out);
    } else {
        gates_prep_kernel<<<512, 256, 0, stream>>>(q, k, v, igw, igb, fgw, fgb,
                                                   ig, fg, nullptr, nullptr);
        scan_kernel<<<BH, 256, 0, stream>>>(ig, fg, aa, MM, nf);
        mlstm_fallback<1><<<256, 256, 0, stream>>>(q, k, v, aa, MM, out, HpartRaw, rsb);
        combine_kernel<1><<<BH * Ss / 4, 256, 0, stream>>>(HpartRaw, rsb, nf, ow, out);
    }
}